// Round 9
// baseline (239.261 us; speedup 1.0000x reference)
//
#include <hip/hip_runtime.h>

// HierarchicalChronoFormer forward, MI355X (gfx950).
// B=8, S=4096, D=512, H=8, dk=64, BIN=64, NB=64, T_BINS=1000.

typedef __attribute__((ext_vector_type(8))) short bf16x8;
typedef __attribute__((ext_vector_type(4))) float f32x4;
typedef __attribute__((ext_vector_type(4))) int i32x4;

#define DEVI __device__ __forceinline__

DEVI unsigned short f2bf(float f) {
  union { float f; unsigned u; } v; v.f = f;
  unsigned r = v.u + 0x7FFFu + ((v.u >> 16) & 1u);
  return (unsigned short)(r >> 16);
}
DEVI float bf2f(unsigned short u) {
  union { unsigned u; float f; } v; v.u = ((unsigned)u) << 16; return v.f;
}

#define GLOAD_LDS16(gp, lp) \
  __builtin_amdgcn_global_load_lds((const __attribute__((address_space(1))) void*)(gp), \
                                   (__attribute__((address_space(3))) void*)(lp), 16, 0, 0)

// ---------------- weight transpose-pack + bias concat.
struct TPackArgs { const float* s[8]; unsigned short* d[8];
                   const float* bs[6]; float* bd[2]; };

__global__ __launch_bounds__(256) void k_tpack8(TPackArgs args) {
  __shared__ float tile[64][65];
  if (blockIdx.x == 512) {
    int t = threadIdx.x;
    for (int i = t; i < 1536; i += 256) {
      int sel = i >> 9, r = i & 511;
      args.bd[0][i] = args.bs[sel][r];
      args.bd[1][i] = args.bs[3 + sel][r];
    }
    return;
  }
  int mat = blockIdx.x >> 6;
  int tl = blockIdx.x & 63;
  const float* W = args.s[mat];
  unsigned short* Wt = args.d[mat];
  int n0 = (tl & 7) << 6, k0 = (tl >> 3) << 6;
  int t = threadIdx.x, j = t & 63, i0 = t >> 6;
#pragma unroll
  for (int rr = 0; rr < 16; ++rr) {
    int i = rr * 4 + i0;
    tile[i][j] = W[(size_t)(k0 + i) * 512 + n0 + j];
  }
  __syncthreads();
#pragma unroll
  for (int rr = 0; rr < 16; ++rr) {
    int i = rr * 4 + i0;
    Wt[(size_t)(n0 + i) * 512 + k0 + j] = f2bf(tile[j][i]);
  }
}

// ---------------- fused time features: coalesced LDS staging, lane owns bin.
__global__ __launch_bounds__(64) void k_time(const float* __restrict__ td, const int* __restrict__ x,
    float* __restrict__ abs_t, float* __restrict__ bin_rel, int* __restrict__ bin_mask,
    int* __restrict__ last_idx) {
  __shared__ float tds[4096];
  __shared__ int xs[4096];
  int b = blockIdx.x, lane = threadIdx.x;
  const f32x4* tp = (const f32x4*)(td + (size_t)b * 4096);
  const i32x4* xp = (const i32x4*)(x + (size_t)b * 4096);
  for (int j = lane; j < 1024; j += 64) {
    f32x4 v = tp[j];
#pragma unroll
    for (int c = 0; c < 4; ++c) v[c] = fmaxf(v[c], 0.f);
    *(f32x4*)&tds[j * 4] = v;
    *(i32x4*)&xs[j * 4] = xp[j];
  }
  __syncthreads();
  float s = 0.f;
  for (int i = 0; i < 64; ++i) s += tds[lane * 64 + i];
  float pre = s;
#pragma unroll
  for (int off = 1; off < 64; off <<= 1) {
    float n = __shfl_up(pre, off, 64);
    if (lane >= off) pre += n;
  }
  float a = pre - s;
  float am = 0.f; int anyv = 0;
  for (int i = 0; i < 64; ++i) {
    a += tds[lane * 64 + i];
    tds[lane * 64 + i] = a;
    if (xs[lane * 64 + i] != 0) { am = fmaxf(am, a); anyv = 1; }
  }
  __syncthreads();
  float* out = abs_t + (size_t)b * 4096;
  for (int j = lane; j < 1024; j += 64)
    *(f32x4*)&out[j * 4] = *(const f32x4*)&tds[j * 4];
  float prev = __shfl_up(am, 1, 64);
  bin_rel[b * 64 + lane] = (lane == 0) ? 0.f : fmaxf(am - prev, 0.f);
  bin_mask[b * 64 + lane] = anyv;
  unsigned long long bal = __ballot(anyv != 0);
  if (lane == 0) last_idx[b] = max(__popcll(bal) - 1, 0);
}

// ---------------- h = ee[x] (0 if x==0) + emb_rel[rb] + emb_abs[ab], bf16 out. 16 tok/block.
__global__ __launch_bounds__(256) void k_embed(const int* __restrict__ x, const float* __restrict__ td,
    const float* __restrict__ abs_t, const float* __restrict__ ee, const float* __restrict__ er,
    const float* __restrict__ ea, unsigned short* __restrict__ h) {
  int t = threadIdx.x;
  int lane = t & 63;
  int c0 = lane * 8;
#pragma unroll
  for (int it = 0; it < 4; ++it) {
    int tok = blockIdx.x * 16 + it * 4 + (t >> 6);
    int xi = x[tok];
    int rb = (int)td[tok]; rb = min(max(rb, 0), 999);
    int ab = (int)abs_t[tok]; ab = min(max(ab, 0), 999);
    const f32x4* pr = (const f32x4*)(er + (size_t)rb * 512 + c0);
    const f32x4* pa = (const f32x4*)(ea + (size_t)ab * 512 + c0);
    f32x4 s0 = pr[0] + pa[0];
    f32x4 s1 = pr[1] + pa[1];
    if (xi != 0) {
      const f32x4* pe = (const f32x4*)(ee + (size_t)xi * 512 + c0);
      s0 += pe[0]; s1 += pe[1];
    }
    bf16x8 o;
#pragma unroll
    for (int i = 0; i < 4; ++i) { o[i] = (short)f2bf(s0[i]); o[4 + i] = (short)f2bf(s1[i]); }
    *(bf16x8*)(h + (size_t)tok * 512 + c0) = o;
  }
}

// ---------------- shared swizzle helper (BK=32 superrow XOR, involution w/ stage)
DEVI bf16x8 lds_frag32(const unsigned short* buf, int r, int g) {
  int sr = r >> 1;
  int slot = (((r & 1) << 2) | g) ^ (sr & 7);
  return *(const bf16x8*)&buf[sr * 64 + slot * 8];
}

// ---------------- big GEMM (QKV): 256x256, BK=32, 4 LDS bufs, depth-3, 8 waves (r6 best).
__global__ __launch_bounds__(512, 2) void k_gemm256(const unsigned short* __restrict__ A,
    const unsigned short* __restrict__ Wt, const float* __restrict__ bias,
    unsigned short* __restrict__ Cout, int N, int tiles_n) {
  __shared__ unsigned short lds[4][2][256 * 32];
  int bid = blockIdx.x;
  { int q = (int)gridDim.x >> 3; bid = (bid & 7) * q + (bid >> 3); }
  int by = bid / tiles_n, bx = bid % tiles_n;
  int m0 = by << 8, n0 = bx << 8;
  int t = threadIdx.x;
  int lane = t & 63, w = t >> 6;
  int wm = w >> 2, wn = w & 3;
  int l15 = lane & 15, l4 = lane >> 4;

  auto stageA = [&](int kt) {
    int k0 = kt << 5;
    unsigned short* dst = &lds[kt & 3][0][0];
#pragma unroll
    for (int l = 0; l < 2; ++l) {
      int pos = l * 512 + t;
      int sr = pos >> 3, slot = pos & 7;
      int gp = slot ^ (sr & 7);
      int row = sr * 2 + (gp >> 2);
      GLOAD_LDS16(&A[(size_t)(m0 + row) * 512 + k0 + (gp & 3) * 8], dst + pos * 8);
    }
  };
  auto stageB = [&](int kt) {
    int k0 = kt << 5;
    unsigned short* dst = &lds[kt & 3][1][0];
#pragma unroll
    for (int l = 0; l < 2; ++l) {
      int pos = l * 512 + t;
      int sr = pos >> 3, slot = pos & 7;
      int gp = slot ^ (sr & 7);
      int row = sr * 2 + (gp >> 2);
      GLOAD_LDS16(&Wt[(size_t)(n0 + row) * 512 + k0 + (gp & 3) * 8], dst + pos * 8);
    }
  };

  f32x4 acc[8][4] = {};
  stageA(0); stageB(0);
  stageA(1); stageB(1);
  stageA(2); stageB(2);

  for (int kt = 0; kt < 16; ++kt) {
    if (kt < 14)       asm volatile("s_waitcnt vmcnt(8)" ::: "memory");
    else if (kt == 14) asm volatile("s_waitcnt vmcnt(4)" ::: "memory");
    else               asm volatile("s_waitcnt vmcnt(0)" ::: "memory");
    __builtin_amdgcn_s_barrier();
    const unsigned short* As = &lds[kt & 3][0][0];
    const unsigned short* Bs = &lds[kt & 3][1][0];

    bf16x8 af[4], bb[4];
#pragma unroll
    for (int i = 0; i < 4; ++i) af[i] = lds_frag32(As, wm * 128 + i * 16 + l15, l4);
#pragma unroll
    for (int j = 0; j < 4; ++j) bb[j] = lds_frag32(Bs, wn * 64 + j * 16 + l15, l4);
    if (kt < 13) stageA(kt + 3);
    __builtin_amdgcn_s_barrier();
    asm volatile("s_waitcnt lgkmcnt(0)" ::: "memory");
    __builtin_amdgcn_sched_barrier(0);
    __builtin_amdgcn_s_setprio(1);
#pragma unroll
    for (int i = 0; i < 4; ++i)
#pragma unroll
      for (int j = 0; j < 4; ++j)
        acc[i][j] = __builtin_amdgcn_mfma_f32_16x16x32_bf16(af[i], bb[j], acc[i][j], 0, 0, 0);
    __builtin_amdgcn_s_setprio(0);

    bf16x8 ah[4];
#pragma unroll
    for (int i = 0; i < 4; ++i) ah[i] = lds_frag32(As, wm * 128 + 64 + i * 16 + l15, l4);
    if (kt < 13) stageB(kt + 3);
    __builtin_amdgcn_s_barrier();
    asm volatile("s_waitcnt lgkmcnt(0)" ::: "memory");
    __builtin_amdgcn_sched_barrier(0);
    __builtin_amdgcn_s_setprio(1);
#pragma unroll
    for (int i = 0; i < 4; ++i)
#pragma unroll
      for (int j = 0; j < 4; ++j)
        acc[4 + i][j] = __builtin_amdgcn_mfma_f32_16x16x32_bf16(ah[i], bb[j], acc[4 + i][j], 0, 0, 0);
    __builtin_amdgcn_s_setprio(0);
  }
#pragma unroll
  for (int i = 0; i < 8; ++i) {
    int rowb = m0 + wm * 128 + i * 16 + (l4 << 2);
#pragma unroll
    for (int j = 0; j < 4; ++j) {
      int col = n0 + wn * 64 + j * 16 + l15;
      float bv = bias[col];
#pragma unroll
      for (int r = 0; r < 4; ++r)
        Cout[(size_t)(rowb + r) * N + col] = f2bf(acc[i][j][r] + bv);
    }
  }
}

// ---------------- FUSED attn + out-proj + LN + masked pool. One block per bin.
// 8 waves = 8 heads. Per wave: QK^T -> softmax(deferred) -> PV -> ctx stripe to LDS;
// then per-wave 64-col stripe of ctx@Wo (K=512, ctx shared in LDS, Wo from L2);
// LN row-stats cross-wave; pool via linearity; write bin_repr[blk].
__global__ __launch_bounds__(512) void k_attnproj(const unsigned short* __restrict__ qkv,
    const float* __restrict__ td, const int* __restrict__ x, const float* __restrict__ temb,
    const unsigned short* __restrict__ WoT, const float* __restrict__ bo,
    const float* __restrict__ g, const float* __restrict__ bt,
    unsigned short* __restrict__ bin_repr) {
  __shared__ unsigned short Vt[8][64][72];       // 73,728 B
  __shared__ unsigned short PsCtx[8 * 64 * 72];  // 73,728 B; Ps[w] slots, later ctx[64][520] overlay
  __shared__ float bias_s[8][64];
  __shared__ int valid_s[64];
  __shared__ float red[64][9];
  __shared__ float meanL[64];
  __shared__ float rstdL[64];
  __shared__ int cntS;
  int blk = blockIdx.x;
  int t = threadIdx.x, w = t >> 6, lane = t & 63;
  int l15 = lane & 15, l4 = lane >> 4;
  size_t base = (size_t)blk * 64;

  if (t < 64) {   // wave 0 entirely
    int v = (x[base + t] != 0) ? 1 : 0;
    valid_s[t] = v;
    int tb = (int)td[base + t];
    tb = min(max(tb, 0), 999);
#pragma unroll
    for (int hh = 0; hh < 8; ++hh) bias_s[hh][t] = temb[tb * 8 + hh];
    unsigned long long bal = __ballot(v != 0);
    if (t == 0) cntS = __popcll(bal);
  }
  {  // stage V transposed for head w: Vt[w][feat][key]
    const unsigned short* vp = qkv + (base + lane) * 1536 + 1024 + w * 64;
#pragma unroll
    for (int f8 = 0; f8 < 8; ++f8) {
      bf16x8 v8 = *(const bf16x8*)(vp + f8 * 8);
#pragma unroll
      for (int j = 0; j < 8; ++j) Vt[w][f8 * 8 + j][lane] = (unsigned short)v8[j];
    }
  }
  __syncthreads();

  // QK^T for head w
  bf16x8 qa[2][4], kb[2][4];
#pragma unroll
  for (int ks = 0; ks < 2; ++ks)
#pragma unroll
    for (int i = 0; i < 4; ++i) {
      int row = i * 16 + l15;
      int kk = ks * 32 + l4 * 8;
      qa[ks][i] = *(const bf16x8*)&qkv[(base + row) * 1536 + w * 64 + kk];
      kb[ks][i] = *(const bf16x8*)&qkv[(base + row) * 1536 + 512 + w * 64 + kk];
    }
  f32x4 acc[4][4] = {};
#pragma unroll
  for (int ks = 0; ks < 2; ++ks)
#pragma unroll
    for (int i = 0; i < 4; ++i)
#pragma unroll
      for (int j = 0; j < 4; ++j)
        acc[i][j] = __builtin_amdgcn_mfma_f32_16x16x32_bf16(qa[ks][i], kb[ks][j], acc[i][j], 0, 0, 0);

  // masked+biased softmax (deferred normalization) -> Ps[w]
  unsigned short* Psw = &PsCtx[w * 64 * 72];
  float invs[4][4];
#pragma unroll
  for (int i = 0; i < 4; ++i) {
#pragma unroll
    for (int r = 0; r < 4; ++r) {
      float sv[4];
#pragma unroll
      for (int j = 0; j < 4; ++j) {
        int key = j * 16 + l15;
        float s = acc[i][j][r] * 0.125f;
        sv[j] = valid_s[key] ? (s + bias_s[w][key]) : -1e9f;
      }
      float m = fmaxf(fmaxf(sv[0], sv[1]), fmaxf(sv[2], sv[3]));
#pragma unroll
      for (int off = 1; off < 16; off <<= 1) m = fmaxf(m, __shfl_xor(m, off, 64));
      float p[4], sum = 0.f;
#pragma unroll
      for (int j = 0; j < 4; ++j) { p[j] = __expf(sv[j] - m); sum += p[j]; }
#pragma unroll
      for (int off = 1; off < 16; off <<= 1) sum += __shfl_xor(sum, off, 64);
      invs[i][r] = 1.f / sum;
      int row = i * 16 + l4 * 4 + r;
#pragma unroll
      for (int j = 0; j < 4; ++j) Psw[row * 72 + j * 16 + l15] = f2bf(p[j]);
    }
  }

  // PV (in-wave LDS deps only)
  f32x4 acc2[4][4] = {};
#pragma unroll
  for (int ks = 0; ks < 2; ++ks) {
    bf16x8 pa[4], vb[4];
    int kk = ks * 32 + l4 * 8;
#pragma unroll
    for (int i = 0; i < 4; ++i) {
      pa[i] = *(const bf16x8*)&Psw[(i * 16 + l15) * 72 + kk];
      vb[i] = *(const bf16x8*)&Vt[w][i * 16 + l15][kk];
    }
#pragma unroll
    for (int i = 0; i < 4; ++i)
#pragma unroll
      for (int j = 0; j < 4; ++j)
        acc2[i][j] = __builtin_amdgcn_mfma_f32_16x16x32_bf16(pa[i], vb[j], acc2[i][j], 0, 0, 0);
  }

  // assemble full ctx [64][520] bf16 in LDS (overlay on Ps region)
  __syncthreads();                         // all waves done reading PsCtx
  unsigned short* ctxl = PsCtx;
#pragma unroll
  for (int i = 0; i < 4; ++i)
#pragma unroll
    for (int j = 0; j < 4; ++j)
#pragma unroll
      for (int r = 0; r < 4; ++r)
        ctxl[(i * 16 + l4 * 4 + r) * 520 + w * 64 + j * 16 + l15] =
            f2bf(acc2[i][j][r] * invs[i][r]);
  __syncthreads();

  // out-proj: wave w computes cols w*64..+63 over K=512 (ctx in LDS, Wo streamed)
  int n0 = w * 64;
  f32x4 acc3[4][4] = {};
#pragma unroll
  for (int kb = 0; kb < 8; ++kb)
#pragma unroll
    for (int ks = 0; ks < 2; ++ks) {
      int kk = kb * 64 + ks * 32 + l4 * 8;
      bf16x8 af[4], bb[4];
#pragma unroll
      for (int i = 0; i < 4; ++i) af[i] = *(const bf16x8*)&ctxl[(i * 16 + l15) * 520 + kk];
#pragma unroll
      for (int j = 0; j < 4; ++j)
        bb[j] = *(const bf16x8*)&WoT[(size_t)(n0 + j * 16 + l15) * 512 + kk];
#pragma unroll
      for (int i = 0; i < 4; ++i)
#pragma unroll
        for (int j = 0; j < 4; ++j)
          acc3[i][j] = __builtin_amdgcn_mfma_f32_16x16x32_bf16(af[i], bb[j], acc3[i][j], 0, 0, 0);
    }

  // LN row stats (cross-wave via red[64][9])
  float bov[4], gv[4], bv[4];
#pragma unroll
  for (int j = 0; j < 4; ++j) {
    int col = n0 + j * 16 + l15;
    bov[j] = bo[col]; gv[j] = g[col]; bv[j] = bt[col];
  }
#pragma unroll
  for (int i = 0; i < 4; ++i)
#pragma unroll
    for (int r = 0; r < 4; ++r) {
      float s = (acc3[i][0][r] + bov[0]) + (acc3[i][1][r] + bov[1]) +
                (acc3[i][2][r] + bov[2]) + (acc3[i][3][r] + bov[3]);
#pragma unroll
      for (int off = 1; off < 16; off <<= 1) s += __shfl_xor(s, off, 64);
      if (l15 == 0) red[i * 16 + l4 * 4 + r][w] = s;
    }
  __syncthreads();
  if (t < 64) {
    float m = 0.f;
#pragma unroll
    for (int ww = 0; ww < 8; ++ww) m += red[t][ww];
    meanL[t] = m * (1.f / 512.f);
  }
  __syncthreads();
#pragma unroll
  for (int i = 0; i < 4; ++i)
#pragma unroll
    for (int r = 0; r < 4; ++r) {
      float m = meanL[i * 16 + l4 * 4 + r];
      float s = 0.f;
#pragma unroll
      for (int j = 0; j < 4; ++j) { float d = acc3[i][j][r] + bov[j] - m; s += d * d; }
#pragma unroll
      for (int off = 1; off < 16; off <<= 1) s += __shfl_xor(s, off, 64);
      if (l15 == 0) red[i * 16 + l4 * 4 + r][w] = s;
    }
  __syncthreads();
  if (t < 64) {
    float vsum = 0.f;
#pragma unroll
    for (int ww = 0; ww < 8; ++ww) vsum += red[t][ww];
    rstdL[t] = rsqrtf(vsum * (1.f / 512.f) + 1e-5f);
  }
  __syncthreads();

  // masked pool: sum_valid LN(y) = g * sum_valid (y-m)*rstd + cnt*bt
  float s4[4] = {0.f, 0.f, 0.f, 0.f};
#pragma unroll
  for (int i = 0; i < 4; ++i)
#pragma unroll
    for (int r = 0; r < 4; ++r) {
      int row = i * 16 + l4 * 4 + r;
      if (valid_s[row]) {
        float m = meanL[row], rs = rstdL[row];
#pragma unroll
        for (int j = 0; j < 4; ++j) s4[j] += (acc3[i][j][r] + bov[j] - m) * rs;
      }
    }
#pragma unroll
  for (int j = 0; j < 4; ++j) {
    s4[j] += __shfl_xor(s4[j], 16, 64);
    s4[j] += __shfl_xor(s4[j], 32, 64);
  }
  int cnt = cntS;
  float denom = fmaxf((float)cnt, 1.f);
  if (l4 == 0) {
#pragma unroll
    for (int j = 0; j < 4; ++j)
      bin_repr[(size_t)blk * 512 + n0 + j * 16 + l15] =
          f2bf((gv[j] * s4[j] + (float)cnt * bv[j]) / denom);
  }
}

// ---------------- small GEMM (inter path): 128x128 tile, reg-staged padded LDS.
__global__ __launch_bounds__(256) void k_gemm(const unsigned short* __restrict__ A,
    const unsigned short* __restrict__ Wt, const float* __restrict__ bias,
    unsigned short* __restrict__ Cout, int N, int tiles_n) {
  __shared__ unsigned short As[128 * 72];
  __shared__ unsigned short Bs[128 * 72];
  int bx = blockIdx.x % tiles_n;
  int by = blockIdx.x / tiles_n;
  int m0 = by << 7, n0 = bx << 7;
  int t = threadIdx.x;
  int lane = t & 63, w = t >> 6;
  int wm = w >> 1, wn = w & 1;
  f32x4 acc[4][4] = {};
  for (int k0 = 0; k0 < 512; k0 += 64) {
    __syncthreads();
#pragma unroll
    for (int i = 0; i < 4; ++i) {
      int idx = t + i * 256;
      int row = idx >> 3, seg = idx & 7;
      *(bf16x8*)&As[row * 72 + seg * 8] = *(const bf16x8*)&A[(size_t)(m0 + row) * 512 + k0 + seg * 8];
      *(bf16x8*)&Bs[row * 72 + seg * 8] = *(const bf16x8*)&Wt[(size_t)(n0 + row) * 512 + k0 + seg * 8];
    }
    __syncthreads();
#pragma unroll
    for (int ks = 0; ks < 2; ++ks) {
      bf16x8 af[4], bb[4];
#pragma unroll
      for (int i = 0; i < 4; ++i) {
        af[i] = *(const bf16x8*)&As[(wm * 64 + i * 16 + (lane & 15)) * 72 + ks * 32 + (lane >> 4) * 8];
        bb[i] = *(const bf16x8*)&Bs[(wn * 64 + i * 16 + (lane & 15)) * 72 + ks * 32 + (lane >> 4) * 8];
      }
#pragma unroll
      for (int i = 0; i < 4; ++i)
#pragma unroll
        for (int j = 0; j < 4; ++j)
          acc[i][j] = __builtin_amdgcn_mfma_f32_16x16x32_bf16(af[i], bb[j], acc[i][j], 0, 0, 0);
    }
  }
#pragma unroll
  for (int i = 0; i < 4; ++i) {
    int rowb = m0 + wm * 64 + i * 16 + ((lane >> 4) << 2);
#pragma unroll
    for (int j = 0; j < 4; ++j) {
      int col = n0 + wn * 64 + j * 16 + (lane & 15);
      float bv = bias[col];
#pragma unroll
      for (int r = 0; r < 4; ++r)
        Cout[(size_t)(rowb + r) * N + col] = f2bf(acc[i][j][r] + bv);
    }
  }
}

// ---------------- small attention (inter path only); 4 heads/block.
__global__ __launch_bounds__(256) void k_attn(const unsigned short* __restrict__ qkv,
    const float* __restrict__ td, const int* __restrict__ validv,
    const float* __restrict__ temb, unsigned short* __restrict__ ctx) {
  __shared__ float bias_s[4][64];
  __shared__ int valid_s[64];
  __shared__ unsigned short P_s[4][64][72];
  __shared__ unsigned short Vt_s[4][64][72];
  int blk = blockIdx.x >> 1, hg = blockIdx.x & 1;
  int t = threadIdx.x, hl = t >> 6, lane = t & 63;
  int h = hg * 4 + hl;
  size_t base = (size_t)blk * 64;
  if (t < 64) {
    valid_s[t] = (validv[base + t] != 0) ? 1 : 0;
    int tb = (int)td[base + t];
    tb = min(max(tb, 0), 999);
#pragma unroll
    for (int hh = 0; hh < 4; ++hh) bias_s[hh][t] = temb[tb * 8 + hg * 4 + hh];
  }
  {
    const unsigned short* vp = qkv + (base + lane) * 1536 + 1024 + h * 64;
#pragma unroll
    for (int f8 = 0; f8 < 8; ++f8) {
      bf16x8 v8 = *(const bf16x8*)(vp + f8 * 8);
#pragma unroll
      for (int j = 0; j < 8; ++j) Vt_s[hl][f8 * 8 + j][lane] = (unsigned short)v8[j];
    }
  }
  __syncthreads();
  bf16x8 qa[2][4], kb[2][4];
#pragma unroll
  for (int ks = 0; ks < 2; ++ks)
#pragma unroll
    for (int i = 0; i < 4; ++i) {
      int row = i * 16 + (lane & 15);
      int kk = ks * 32 + (lane >> 4) * 8;
      qa[ks][i] = *(const bf16x8*)&qkv[(base + row) * 1536 + h * 64 + kk];
      kb[ks][i] = *(const bf16x8*)&qkv[(base + row) * 1536 + 512 + h * 64 + kk];
    }
  f32x4 acc[4][4] = {};
#pragma unroll
  for (int ks = 0; ks < 2; ++ks)
#pragma unroll
    for (int i = 0; i < 4; ++i)
#pragma unroll
      for (int j = 0; j < 4; ++j)
        acc[i][j] = __builtin_amdgcn_mfma_f32_16x16x32_bf16(qa[ks][i], kb[ks][j], acc[i][j], 0, 0, 0);
  float invs[4][4];
#pragma unroll
  for (int i = 0; i < 4; ++i) {
#pragma unroll
    for (int r = 0; r < 4; ++r) {
      float sv[4];
#pragma unroll
      for (int j = 0; j < 4; ++j) {
        int key = j * 16 + (lane & 15);
        float s = acc[i][j][r] * 0.125f;
        sv[j] = valid_s[key] ? (s + bias_s[hl][key]) : -1e9f;
      }
      float m = fmaxf(fmaxf(sv[0], sv[1]), fmaxf(sv[2], sv[3]));
#pragma unroll
      for (int off = 1; off < 16; off <<= 1) m = fmaxf(m, __shfl_xor(m, off, 64));
      float p[4], sum = 0.f;
#pragma unroll
      for (int j = 0; j < 4; ++j) { p[j] = __expf(sv[j] - m); sum += p[j]; }
#pragma unroll
      for (int off = 1; off < 16; off <<= 1) sum += __shfl_xor(sum, off, 64);
      invs[i][r] = 1.f / sum;
      int row = i * 16 + ((lane >> 4) << 2) + r;
#pragma unroll
      for (int j = 0; j < 4; ++j) P_s[hl][row][j * 16 + (lane & 15)] = f2bf(p[j]);
    }
  }
  __syncthreads();
  f32x4 acc2[4][4] = {};
#pragma unroll
  for (int ks = 0; ks < 2; ++ks) {
    bf16x8 pa[4], vb[4];
    int kk = ks * 32 + (lane >> 4) * 8;
#pragma unroll
    for (int i = 0; i < 4; ++i) {
      pa[i] = *(const bf16x8*)&P_s[hl][i * 16 + (lane & 15)][kk];
      vb[i] = *(const bf16x8*)&Vt_s[hl][i * 16 + (lane & 15)][kk];
    }
#pragma unroll
    for (int i = 0; i < 4; ++i)
#pragma unroll
      for (int j = 0; j < 4; ++j)
        acc2[i][j] = __builtin_amdgcn_mfma_f32_16x16x32_bf16(pa[i], vb[j], acc2[i][j], 0, 0, 0);
  }
#pragma unroll
  for (int i = 0; i < 4; ++i) {
    int rowb = i * 16 + ((lane >> 4) << 2);
#pragma unroll
    for (int j = 0; j < 4; ++j) {
      int col = h * 64 + j * 16 + (lane & 15);
#pragma unroll
      for (int r = 0; r < 4; ++r)
        ctx[(base + rowb + r) * 512 + col] = f2bf(acc2[i][j][r] * invs[i][r]);
    }
  }
}

// ---------------- final: select last row, LN(e_g,e_bt), MLP, sigmoid. grid 8.
__global__ __launch_bounds__(256) void k_final(const unsigned short* __restrict__ proj2,
    const int* __restrict__ last_idx, const float* __restrict__ g, const float* __restrict__ bt,
    const float* __restrict__ w1, const float* __restrict__ b1,
    const float* __restrict__ w2, const float* __restrict__ b2, float* __restrict__ outp) {
  __shared__ float row_s[512];
  __shared__ float red_s[4];
  __shared__ float red2_s[4];
  int b = blockIdx.x, t = threadIdx.x;
  const unsigned short* rp = proj2 + (size_t)(b * 64 + last_idx[b]) * 512;
  float v0 = bf2f(rp[t]), v1 = bf2f(rp[t + 256]);
  float s = v0 + v1;
#pragma unroll
  for (int off = 1; off < 64; off <<= 1) s += __shfl_xor(s, off, 64);
  if ((t & 63) == 0) red_s[t >> 6] = s;
  __syncthreads();
  float mean = (red_s[0] + red_s[1] + red_s[2] + red_s[3]) * (1.f / 512.f);
  float d0 = v0 - mean, d1 = v1 - mean;
  float vs = d0 * d0 + d1 * d1;
#pragma unroll
  for (int off = 1; off < 64; off <<= 1) vs += __shfl_xor(vs, off, 64);
  if ((t & 63) == 0) red2_s[t >> 6] = vs;
  __syncthreads();
  float rstd = rsqrtf((red2_s[0] + red2_s[1] + red2_s[2] + red2_s[3]) * (1.f / 512.f) + 1e-5f);
  row_s[t]       = d0 * rstd * g[t]       + bt[t];
  row_s[t + 256] = d1 * rstd * g[t + 256] + bt[t + 256];
  __syncthreads();
  float acc = b1[t];
  for (int k = 0; k < 512; ++k) acc += row_s[k] * w1[(size_t)k * 256 + t];
  float hv = fmaxf(acc, 0.f) * w2[t];
#pragma unroll
  for (int off = 1; off < 64; off <<= 1) hv += __shfl_xor(hv, off, 64);
  if ((t & 63) == 0) red_s[t >> 6] = hv;
  __syncthreads();
  if (t == 0) {
    float o = red_s[0] + red_s[1] + red_s[2] + red_s[3] + b2[0];
    outp[b] = 1.f / (1.f + __expf(-o));
  }
}

extern "C" void kernel_launch(void* const* d_in, const int* in_sizes, int n_in,
                              void* d_out, int out_size, void* d_ws, size_t ws_size,
                              hipStream_t stream) {
  const int*   x    = (const int*)d_in[0];
  const float* td   = (const float*)d_in[1];
  const float* ee   = (const float*)d_in[2];
  const float* er   = (const float*)d_in[3];
  const float* ea   = (const float*)d_in[4];
  const float* iq_w = (const float*)d_in[5];  const float* iq_b = (const float*)d_in[6];
  const float* ik_w = (const float*)d_in[7];  const float* ik_b = (const float*)d_in[8];
  const float* iv_w = (const float*)d_in[9];  const float* iv_b = (const float*)d_in[10];
  const float* io_w = (const float*)d_in[11]; const float* io_b = (const float*)d_in[12];
  const float* eq_w = (const float*)d_in[13]; const float* eq_b = (const float*)d_in[14];
  const float* ek_w = (const float*)d_in[15]; const float* ek_b = (const float*)d_in[16];
  const float* ev_w = (const float*)d_in[17]; const float* ev_b = (const float*)d_in[18];
  const float* eo_w = (const float*)d_in[19]; const float* eo_b = (const float*)d_in[20];
  const float* i_temb = (const float*)d_in[21];
  const float* e_temb = (const float*)d_in[22];
  const float* i_g  = (const float*)d_in[23]; const float* i_bt = (const float*)d_in[24];
  const float* e_g  = (const float*)d_in[25]; const float* e_bt = (const float*)d_in[26];
  const float* w1   = (const float*)d_in[27]; const float* b1   = (const float*)d_in[28];
  const float* w2   = (const float*)d_in[29]; const float* b2   = (const float*)d_in[30];

  char* ws = (char*)d_ws;
  size_t off = 0;
  auto alloc = [&](size_t nb) { size_t r = off; off += (nb + 255) & ~(size_t)255; return r; };
  float* abs_t    = (float*)(ws + alloc((size_t)32768 * 4));
  float* bin_rel  = (float*)(ws + alloc(512 * 4));
  int*   bin_mask = (int*)(ws + alloc(512 * 4));
  int*   last_idx = (int*)(ws + alloc(64));
  unsigned short* wqkv_i = (unsigned short*)(ws + alloc((size_t)1536 * 512 * 2));
  unsigned short* wo_i   = (unsigned short*)(ws + alloc((size_t)512 * 512 * 2));
  unsigned short* wqkv_e = (unsigned short*)(ws + alloc((size_t)1536 * 512 * 2));
  unsigned short* wo_e   = (unsigned short*)(ws + alloc((size_t)512 * 512 * 2));
  float* bqkv_i = (float*)(ws + alloc(1536 * 4));
  float* bqkv_e = (float*)(ws + alloc(1536 * 4));
  unsigned short* hbuf = (unsigned short*)(ws + alloc((size_t)32768 * 512 * 2));
  unsigned short* qkvbuf = (unsigned short*)(ws + alloc((size_t)32768 * 1536 * 2));
  unsigned short* bin_repr = (unsigned short*)(ws + alloc((size_t)512 * 512 * 2));
  char* small = ws + alloc((size_t)512 * 1536 * 2);                                // qkv2, then proj2
  unsigned short* qkv2 = (unsigned short*)small;
  unsigned short* proj2 = (unsigned short*)small;
  unsigned short* ctx2 = (unsigned short*)(ws + alloc((size_t)512 * 512 * 2));

  // 1. pack weights + bias concats
  TPackArgs tp;
  tp.s[0] = iq_w; tp.d[0] = wqkv_i;
  tp.s[1] = ik_w; tp.d[1] = wqkv_i + (size_t)512 * 512;
  tp.s[2] = iv_w; tp.d[2] = wqkv_i + (size_t)1024 * 512;
  tp.s[3] = io_w; tp.d[3] = wo_i;
  tp.s[4] = eq_w; tp.d[4] = wqkv_e;
  tp.s[5] = ek_w; tp.d[5] = wqkv_e + (size_t)512 * 512;
  tp.s[6] = ev_w; tp.d[6] = wqkv_e + (size_t)1024 * 512;
  tp.s[7] = eo_w; tp.d[7] = wo_e;
  tp.bs[0] = iq_b; tp.bs[1] = ik_b; tp.bs[2] = iv_b;
  tp.bs[3] = eq_b; tp.bs[4] = ek_b; tp.bs[5] = ev_b;
  tp.bd[0] = bqkv_i; tp.bd[1] = bqkv_e;
  k_tpack8<<<513, 256, 0, stream>>>(tp);

  // 2. time features
  k_time<<<8, 64, 0, stream>>>(td, x, abs_t, bin_rel, bin_mask, last_idx);

  // 3. embeddings -> h
  k_embed<<<2048, 256, 0, stream>>>(x, td, abs_t, ee, er, ea, hbuf);

  // 4. intra path: QKV GEMM, then fused attn+oproj+LN+pool (one block per bin)
  k_gemm256<<<128 * 6, 512, 0, stream>>>(hbuf, wqkv_i, bqkv_i, qkvbuf, 1536, 6);
  k_attnproj<<<512, 512, 0, stream>>>(qkvbuf, td, x, i_temb, wo_i, io_b, i_g, i_bt, bin_repr);

  // 5. inter path
  k_gemm<<<4 * 12, 256, 0, stream>>>(bin_repr, wqkv_e, bqkv_e, qkv2, 1536, 12);
  k_attn<<<16, 256, 0, stream>>>(qkv2, bin_rel, bin_mask, e_temb, ctx2);
  k_gemm<<<4 * 4, 256, 0, stream>>>(ctx2, wo_e, eo_b, proj2, 512, 4);

  // 6. head
  k_final<<<8, 256, 0, stream>>>(proj2, last_idx, e_g, e_bt, w1, b1, w2, b2, (float*)d_out);
}

// Round 10
// 228.605 us; speedup vs baseline: 1.0466x; 1.0466x over previous
//
#include <hip/hip_runtime.h>

// HierarchicalChronoFormer forward, MI355X (gfx950).
// B=8, S=4096, D=512, H=8, dk=64, BIN=64, NB=64, T_BINS=1000.

typedef __attribute__((ext_vector_type(8))) short bf16x8;
typedef __attribute__((ext_vector_type(4))) float f32x4;
typedef __attribute__((ext_vector_type(4))) int i32x4;

#define DEVI __device__ __forceinline__

DEVI unsigned short f2bf(float f) {
  union { float f; unsigned u; } v; v.f = f;
  unsigned r = v.u + 0x7FFFu + ((v.u >> 16) & 1u);
  return (unsigned short)(r >> 16);
}
DEVI float bf2f(unsigned short u) {
  union { unsigned u; float f; } v; v.u = ((unsigned)u) << 16; return v.f;
}

#define GLOAD_LDS16(gp, lp) \
  __builtin_amdgcn_global_load_lds((const __attribute__((address_space(1))) void*)(gp), \
                                   (__attribute__((address_space(3))) void*)(lp), 16, 0, 0)

// ---------------- weight transpose-pack + bias concat.
struct TPackArgs { const float* s[8]; unsigned short* d[8];
                   const float* bs[6]; float* bd[2]; };

__global__ __launch_bounds__(256) void k_tpack8(TPackArgs args) {
  __shared__ float tile[64][65];
  if (blockIdx.x == 512) {
    int t = threadIdx.x;
    for (int i = t; i < 1536; i += 256) {
      int sel = i >> 9, r = i & 511;
      args.bd[0][i] = args.bs[sel][r];
      args.bd[1][i] = args.bs[3 + sel][r];
    }
    return;
  }
  int mat = blockIdx.x >> 6;
  int tl = blockIdx.x & 63;
  const float* W = args.s[mat];
  unsigned short* Wt = args.d[mat];
  int n0 = (tl & 7) << 6, k0 = (tl >> 3) << 6;
  int t = threadIdx.x, j = t & 63, i0 = t >> 6;
#pragma unroll
  for (int rr = 0; rr < 16; ++rr) {
    int i = rr * 4 + i0;
    tile[i][j] = W[(size_t)(k0 + i) * 512 + n0 + j];
  }
  __syncthreads();
#pragma unroll
  for (int rr = 0; rr < 16; ++rr) {
    int i = rr * 4 + i0;
    Wt[(size_t)(n0 + i) * 512 + k0 + j] = f2bf(tile[j][i]);
  }
}

// ---------------- fused time features: coalesced LDS staging, lane owns bin.
__global__ __launch_bounds__(64) void k_time(const float* __restrict__ td, const int* __restrict__ x,
    float* __restrict__ abs_t, float* __restrict__ bin_rel, int* __restrict__ bin_mask,
    int* __restrict__ last_idx) {
  __shared__ float tds[4096];
  __shared__ int xs[4096];
  int b = blockIdx.x, lane = threadIdx.x;
  const f32x4* tp = (const f32x4*)(td + (size_t)b * 4096);
  const i32x4* xp = (const i32x4*)(x + (size_t)b * 4096);
  for (int j = lane; j < 1024; j += 64) {
    f32x4 v = tp[j];
#pragma unroll
    for (int c = 0; c < 4; ++c) v[c] = fmaxf(v[c], 0.f);
    *(f32x4*)&tds[j * 4] = v;
    *(i32x4*)&xs[j * 4] = xp[j];
  }
  __syncthreads();
  float s = 0.f;
  for (int i = 0; i < 64; ++i) s += tds[lane * 64 + i];
  float pre = s;
#pragma unroll
  for (int off = 1; off < 64; off <<= 1) {
    float n = __shfl_up(pre, off, 64);
    if (lane >= off) pre += n;
  }
  float a = pre - s;
  float am = 0.f; int anyv = 0;
  for (int i = 0; i < 64; ++i) {
    a += tds[lane * 64 + i];
    tds[lane * 64 + i] = a;
    if (xs[lane * 64 + i] != 0) { am = fmaxf(am, a); anyv = 1; }
  }
  __syncthreads();
  float* out = abs_t + (size_t)b * 4096;
  for (int j = lane; j < 1024; j += 64)
    *(f32x4*)&out[j * 4] = *(const f32x4*)&tds[j * 4];
  float prev = __shfl_up(am, 1, 64);
  bin_rel[b * 64 + lane] = (lane == 0) ? 0.f : fmaxf(am - prev, 0.f);
  bin_mask[b * 64 + lane] = anyv;
  unsigned long long bal = __ballot(anyv != 0);
  if (lane == 0) last_idx[b] = max(__popcll(bal) - 1, 0);
}

// ---------------- h = ee[x] (0 if x==0) + emb_rel[rb] + emb_abs[ab], bf16 out. 16 tok/block.
__global__ __launch_bounds__(256) void k_embed(const int* __restrict__ x, const float* __restrict__ td,
    const float* __restrict__ abs_t, const float* __restrict__ ee, const float* __restrict__ er,
    const float* __restrict__ ea, unsigned short* __restrict__ h) {
  int t = threadIdx.x;
  int lane = t & 63;
  int c0 = lane * 8;
#pragma unroll
  for (int it = 0; it < 4; ++it) {
    int tok = blockIdx.x * 16 + it * 4 + (t >> 6);
    int xi = x[tok];
    int rb = (int)td[tok]; rb = min(max(rb, 0), 999);
    int ab = (int)abs_t[tok]; ab = min(max(ab, 0), 999);
    const f32x4* pr = (const f32x4*)(er + (size_t)rb * 512 + c0);
    const f32x4* pa = (const f32x4*)(ea + (size_t)ab * 512 + c0);
    f32x4 s0 = pr[0] + pa[0];
    f32x4 s1 = pr[1] + pa[1];
    if (xi != 0) {
      const f32x4* pe = (const f32x4*)(ee + (size_t)xi * 512 + c0);
      s0 += pe[0]; s1 += pe[1];
    }
    bf16x8 o;
#pragma unroll
    for (int i = 0; i < 4; ++i) { o[i] = (short)f2bf(s0[i]); o[4 + i] = (short)f2bf(s1[i]); }
    *(bf16x8*)(h + (size_t)tok * 512 + c0) = o;
  }
}

// ---------------- shared swizzle helper (BK=32 superrow XOR, involution w/ stage)
DEVI bf16x8 lds_frag32(const unsigned short* buf, int r, int g) {
  int sr = r >> 1;
  int slot = (((r & 1) << 2) | g) ^ (sr & 7);
  return *(const bf16x8*)&buf[sr * 64 + slot * 8];
}

// ---------------- big GEMM (QKV): 256x256, BK=32, **2 LDS bufs (64KB) -> 2 blocks/CU**.
// Depth-1 prefetch; cross-block wave overlap absorbs the vmcnt(0)+barrier drains.
__global__ __launch_bounds__(512, 2) void k_gemm256(const unsigned short* __restrict__ A,
    const unsigned short* __restrict__ Wt, const float* __restrict__ bias,
    unsigned short* __restrict__ Cout, int N, int tiles_n) {
  __shared__ unsigned short lds[2][2][256 * 32];   // 64 KB
  int bid = blockIdx.x;
  { int q = (int)gridDim.x >> 3; bid = (bid & 7) * q + (bid >> 3); }
  int by = bid / tiles_n, bx = bid % tiles_n;
  int m0 = by << 8, n0 = bx << 8;
  int t = threadIdx.x;
  int lane = t & 63, w = t >> 6;
  int wm = w >> 2, wn = w & 3;
  int l15 = lane & 15, l4 = lane >> 4;

  auto stageA = [&](int kt) {
    int k0 = kt << 5;
    unsigned short* dst = &lds[kt & 1][0][0];
#pragma unroll
    for (int l = 0; l < 2; ++l) {
      int pos = l * 512 + t;
      int sr = pos >> 3, slot = pos & 7;
      int gp = slot ^ (sr & 7);
      int row = sr * 2 + (gp >> 2);
      GLOAD_LDS16(&A[(size_t)(m0 + row) * 512 + k0 + (gp & 3) * 8], dst + pos * 8);
    }
  };
  auto stageB = [&](int kt) {
    int k0 = kt << 5;
    unsigned short* dst = &lds[kt & 1][1][0];
#pragma unroll
    for (int l = 0; l < 2; ++l) {
      int pos = l * 512 + t;
      int sr = pos >> 3, slot = pos & 7;
      int gp = slot ^ (sr & 7);
      int row = sr * 2 + (gp >> 2);
      GLOAD_LDS16(&Wt[(size_t)(n0 + row) * 512 + k0 + (gp & 3) * 8], dst + pos * 8);
    }
  };

  f32x4 acc[8][4] = {};
  stageA(0); stageB(0);

  for (int kt = 0; kt < 16; ++kt) {
    asm volatile("s_waitcnt vmcnt(0)" ::: "memory");   // buf[kt&1] landed
    __builtin_amdgcn_s_barrier();
    const unsigned short* As = &lds[kt & 1][0][0];
    const unsigned short* Bs = &lds[kt & 1][1][0];

    // phase A: rows 0..63 of wave tile x 64 cols
    bf16x8 af[4], bb[4];
#pragma unroll
    for (int i = 0; i < 4; ++i) af[i] = lds_frag32(As, wm * 128 + i * 16 + l15, l4);
#pragma unroll
    for (int j = 0; j < 4; ++j) bb[j] = lds_frag32(Bs, wn * 64 + j * 16 + l15, l4);
    if (kt < 15) stageA(kt + 1);          // safe: all waves past kt-top barrier
    __builtin_amdgcn_s_barrier();
    asm volatile("s_waitcnt lgkmcnt(0)" ::: "memory");
    __builtin_amdgcn_sched_barrier(0);
    __builtin_amdgcn_s_setprio(1);
#pragma unroll
    for (int i = 0; i < 4; ++i)
#pragma unroll
      for (int j = 0; j < 4; ++j)
        acc[i][j] = __builtin_amdgcn_mfma_f32_16x16x32_bf16(af[i], bb[j], acc[i][j], 0, 0, 0);
    __builtin_amdgcn_s_setprio(0);

    // phase B: rows 64..127 of wave tile x 64 cols
    bf16x8 ah[4];
#pragma unroll
    for (int i = 0; i < 4; ++i) ah[i] = lds_frag32(As, wm * 128 + 64 + i * 16 + l15, l4);
    if (kt < 15) stageB(kt + 1);
    __builtin_amdgcn_s_barrier();
    asm volatile("s_waitcnt lgkmcnt(0)" ::: "memory");
    __builtin_amdgcn_sched_barrier(0);
    __builtin_amdgcn_s_setprio(1);
#pragma unroll
    for (int i = 0; i < 4; ++i)
#pragma unroll
      for (int j = 0; j < 4; ++j)
        acc[4 + i][j] = __builtin_amdgcn_mfma_f32_16x16x32_bf16(ah[i], bb[j], acc[4 + i][j], 0, 0, 0);
    __builtin_amdgcn_s_setprio(0);
  }
#pragma unroll
  for (int i = 0; i < 8; ++i) {
    int rowb = m0 + wm * 128 + i * 16 + (l4 << 2);
#pragma unroll
    for (int j = 0; j < 4; ++j) {
      int col = n0 + wn * 64 + j * 16 + l15;
      float bv = bias[col];
#pragma unroll
      for (int r = 0; r < 4; ++r)
        Cout[(size_t)(rowb + r) * N + col] = f2bf(acc[i][j][r] + bv);
    }
  }
}

// ---------------- fused out-proj + LN + masked pool (r6 version): BM=128, BN=512 (all Wo),
// BK=32. A 4-buf (32KB) + B 2-buf (64KB). 8 waves (1Mx8N).
__global__ __launch_bounds__(512, 2) void k_oproj(const unsigned short* __restrict__ ctx,
    const unsigned short* __restrict__ WoT, const float* __restrict__ bo,
    const int* __restrict__ x, const float* __restrict__ g, const float* __restrict__ bt,
    unsigned short* __restrict__ bin_repr) {
  __shared__ unsigned short ldsA[4][128 * 32];
  __shared__ unsigned short ldsB[2][512 * 32];
  int bid = blockIdx.x;
  { int q = (int)gridDim.x >> 3; bid = (bid & 7) * q + (bid >> 3); }  // grid 256 %8==0
  int m0 = bid << 7;
  int t = threadIdx.x;
  int lane = t & 63, w = t >> 6;          // w = wn (cols w*64..+63), rows 0..127 all waves
  int l15 = lane & 15, l4 = lane >> 4;

  auto stageA = [&](int kt) {
    int k0 = kt << 5;
    unsigned short* dst = &ldsA[kt & 3][0];
    int pos = t;
    int sr = pos >> 3, slot = pos & 7;
    int gp = slot ^ (sr & 7);
    int row = sr * 2 + (gp >> 2);
    GLOAD_LDS16(&ctx[(size_t)(m0 + row) * 512 + k0 + (gp & 3) * 8], dst + pos * 8);
  };
  auto stageB = [&](int kt) {
    int k0 = kt << 5;
    unsigned short* dst = &ldsB[kt & 1][0];
#pragma unroll
    for (int l = 0; l < 4; ++l) {
      int pos = l * 512 + t;
      int sr = pos >> 3, slot = pos & 7;
      int gp = slot ^ (sr & 7);
      int row = sr * 2 + (gp >> 2);
      GLOAD_LDS16(&WoT[(size_t)row * 512 + k0 + (gp & 3) * 8], dst + pos * 8);
    }
  };

  f32x4 acc[8][4] = {};
  // prologue: B0, A0, A1, A2, B1  (11 loads)
  stageB(0); stageA(0); stageA(1); stageA(2); stageB(1);

  for (int kt = 0; kt < 16; ++kt) {
    if (kt == 0)      asm volatile("s_waitcnt vmcnt(6)" ::: "memory");
    else if (kt < 14) asm volatile("s_waitcnt vmcnt(1)" ::: "memory");
    else              asm volatile("s_waitcnt vmcnt(0)" ::: "memory");
    __builtin_amdgcn_s_barrier();
    const unsigned short* As = &ldsA[kt & 3][0];
    const unsigned short* Bs = &ldsB[kt & 1][0];

    bf16x8 af[4], bb[4];
#pragma unroll
    for (int i = 0; i < 4; ++i) af[i] = lds_frag32(As, i * 16 + l15, l4);
#pragma unroll
    for (int j = 0; j < 4; ++j) bb[j] = lds_frag32(Bs, w * 64 + j * 16 + l15, l4);
    if (kt >= 1 && kt <= 14) stageB(kt + 1);
    __builtin_amdgcn_s_barrier();
    asm volatile("s_waitcnt lgkmcnt(0)" ::: "memory");
    __builtin_amdgcn_sched_barrier(0);
    __builtin_amdgcn_s_setprio(1);
#pragma unroll
    for (int i = 0; i < 4; ++i)
#pragma unroll
      for (int j = 0; j < 4; ++j)
        acc[i][j] = __builtin_amdgcn_mfma_f32_16x16x32_bf16(af[i], bb[j], acc[i][j], 0, 0, 0);
    __builtin_amdgcn_s_setprio(0);

    bf16x8 ah[4];
#pragma unroll
    for (int i = 0; i < 4; ++i) ah[i] = lds_frag32(As, 64 + i * 16 + l15, l4);
    if (kt <= 12) stageA(kt + 3);
    __builtin_amdgcn_s_barrier();
    asm volatile("s_waitcnt lgkmcnt(0)" ::: "memory");
    __builtin_amdgcn_sched_barrier(0);
    __builtin_amdgcn_s_setprio(1);
#pragma unroll
    for (int i = 0; i < 4; ++i)
#pragma unroll
      for (int j = 0; j < 4; ++j)
        acc[4 + i][j] = __builtin_amdgcn_mfma_f32_16x16x32_bf16(ah[i], bb[j], acc[4 + i][j], 0, 0, 0);
    __builtin_amdgcn_s_setprio(0);
  }

  // -------- epilogue: bias + LN (f32) + masked mean-pool of 2 bins -> bin_repr
  __syncthreads();                       // all LDS reads done; reuse ldsA region
  float* red   = (float*)&ldsA[0][0];    // [128][9]
  float* meanL = red + 128 * 9;          // [128]
  float* rstdL = meanL + 128;            // [128]
  int*   valL  = (int*)(rstdL + 128);    // [128]
  int*   cntL  = valL + 128;             // [2]

  int cols[4]; float bov[4], gv[4], bv[4];
#pragma unroll
  for (int j = 0; j < 4; ++j) {
    cols[j] = w * 64 + j * 16 + l15;
    bov[j] = bo[cols[j]]; gv[j] = g[cols[j]]; bv[j] = bt[cols[j]];
  }
  if (t < 128) {
    int v = (x[m0 + t] != 0) ? 1 : 0;
    valL[t] = v;
    unsigned long long bal = __ballot(v != 0);   // wave 0 = bin0 rows, wave 1 = bin1 rows
    if ((t & 63) == 0) cntL[t >> 6] = __popcll(bal);
  }
  // pass 1: row sums
#pragma unroll
  for (int i = 0; i < 8; ++i)
#pragma unroll
    for (int r = 0; r < 4; ++r) {
      float s = (acc[i][0][r] + bov[0]) + (acc[i][1][r] + bov[1]) +
                (acc[i][2][r] + bov[2]) + (acc[i][3][r] + bov[3]);
#pragma unroll
      for (int off = 1; off < 16; off <<= 1) s += __shfl_xor(s, off, 64);
      if (l15 == 0) red[(i * 16 + l4 * 4 + r) * 9 + w] = s;
    }
  __syncthreads();
  if (t < 128) {
    float m = 0.f;
#pragma unroll
    for (int ww = 0; ww < 8; ++ww) m += red[t * 9 + ww];
    meanL[t] = m * (1.f / 512.f);
  }
  __syncthreads();
  // pass 2: row variance
#pragma unroll
  for (int i = 0; i < 8; ++i)
#pragma unroll
    for (int r = 0; r < 4; ++r) {
      float m = meanL[i * 16 + l4 * 4 + r];
      float s = 0.f;
#pragma unroll
      for (int j = 0; j < 4; ++j) { float d = acc[i][j][r] + bov[j] - m; s += d * d; }
#pragma unroll
      for (int off = 1; off < 16; off <<= 1) s += __shfl_xor(s, off, 64);
      if (l15 == 0) red[(i * 16 + l4 * 4 + r) * 9 + w] = s;
    }
  __syncthreads();
  if (t < 128) {
    float vsum = 0.f;
#pragma unroll
    for (int ww = 0; ww < 8; ++ww) vsum += red[t * 9 + ww];
    rstdL[t] = rsqrtf(vsum * (1.f / 512.f) + 1e-5f);
  }
  __syncthreads();
  // pool: y = (val-mean)*rstd*g + bt, masked by valid row; bins = rows 0-63 / 64-127
  float p0[4] = {0.f, 0.f, 0.f, 0.f}, p1[4] = {0.f, 0.f, 0.f, 0.f};
#pragma unroll
  for (int i = 0; i < 8; ++i)
#pragma unroll
    for (int r = 0; r < 4; ++r) {
      int row = i * 16 + l4 * 4 + r;
      if (valL[row]) {
        float m = meanL[row], rs = rstdL[row];
#pragma unroll
        for (int j = 0; j < 4; ++j) {
          float y = (acc[i][j][r] + bov[j] - m) * rs * gv[j] + bv[j];
          if (i < 4) p0[j] += y; else p1[j] += y;
        }
      }
    }
#pragma unroll
  for (int j = 0; j < 4; ++j) {
    p0[j] += __shfl_xor(p0[j], 16, 64); p0[j] += __shfl_xor(p0[j], 32, 64);
    p1[j] += __shfl_xor(p1[j], 16, 64); p1[j] += __shfl_xor(p1[j], 32, 64);
  }
  float d0 = 1.f / fmaxf((float)cntL[0], 1.f);
  float d1 = 1.f / fmaxf((float)cntL[1], 1.f);
  if (l4 == 0) {
    int binr = (m0 >> 6);
#pragma unroll
    for (int j = 0; j < 4; ++j) {
      bin_repr[(size_t)binr * 512 + cols[j]]       = f2bf(p0[j] * d0);
      bin_repr[(size_t)(binr + 1) * 512 + cols[j]] = f2bf(p1[j] * d1);
    }
  }
}

// ---------------- small GEMM (inter path): 128x128 tile, reg-staged padded LDS.
__global__ __launch_bounds__(256) void k_gemm(const unsigned short* __restrict__ A,
    const unsigned short* __restrict__ Wt, const float* __restrict__ bias,
    unsigned short* __restrict__ Cout, int N, int tiles_n) {
  __shared__ unsigned short As[128 * 72];
  __shared__ unsigned short Bs[128 * 72];
  int bx = blockIdx.x % tiles_n;
  int by = blockIdx.x / tiles_n;
  int m0 = by << 7, n0 = bx << 7;
  int t = threadIdx.x;
  int lane = t & 63, w = t >> 6;
  int wm = w >> 1, wn = w & 1;
  f32x4 acc[4][4] = {};
  for (int k0 = 0; k0 < 512; k0 += 64) {
    __syncthreads();
#pragma unroll
    for (int i = 0; i < 4; ++i) {
      int idx = t + i * 256;
      int row = idx >> 3, seg = idx & 7;
      *(bf16x8*)&As[row * 72 + seg * 8] = *(const bf16x8*)&A[(size_t)(m0 + row) * 512 + k0 + seg * 8];
      *(bf16x8*)&Bs[row * 72 + seg * 8] = *(const bf16x8*)&Wt[(size_t)(n0 + row) * 512 + k0 + seg * 8];
    }
    __syncthreads();
#pragma unroll
    for (int ks = 0; ks < 2; ++ks) {
      bf16x8 af[4], bb[4];
#pragma unroll
      for (int i = 0; i < 4; ++i) {
        af[i] = *(const bf16x8*)&As[(wm * 64 + i * 16 + (lane & 15)) * 72 + ks * 32 + (lane >> 4) * 8];
        bb[i] = *(const bf16x8*)&Bs[(wn * 64 + i * 16 + (lane & 15)) * 72 + ks * 32 + (lane >> 4) * 8];
      }
#pragma unroll
      for (int i = 0; i < 4; ++i)
#pragma unroll
        for (int j = 0; j < 4; ++j)
          acc[i][j] = __builtin_amdgcn_mfma_f32_16x16x32_bf16(af[i], bb[j], acc[i][j], 0, 0, 0);
    }
  }
#pragma unroll
  for (int i = 0; i < 4; ++i) {
    int rowb = m0 + wm * 64 + i * 16 + ((lane >> 4) << 2);
#pragma unroll
    for (int j = 0; j < 4; ++j) {
      int col = n0 + wn * 64 + j * 16 + (lane & 15);
      float bv = bias[col];
#pragma unroll
      for (int r = 0; r < 4; ++r)
        Cout[(size_t)(rowb + r) * N + col] = f2bf(acc[i][j][r] + bv);
    }
  }
}

// ---------------- fused attention; block = 4 heads of one 64-token bin (2 blocks/bin).
// Deferred softmax normalization; coalesced LDS-transpose epilogue.
__global__ __launch_bounds__(256) void k_attn(const unsigned short* __restrict__ qkv,
    const float* __restrict__ td, const int* __restrict__ validv,
    const float* __restrict__ temb, unsigned short* __restrict__ ctx) {
  __shared__ float bias_s[4][64];
  __shared__ int valid_s[64];
  __shared__ unsigned short P_s[4][64][72];
  __shared__ unsigned short Vt_s[4][64][72];
  int blk = blockIdx.x >> 1, hg = blockIdx.x & 1;
  int t = threadIdx.x, hl = t >> 6, lane = t & 63;
  int h = hg * 4 + hl;
  size_t base = (size_t)blk * 64;
  if (t < 64) {
    valid_s[t] = (validv[base + t] != 0) ? 1 : 0;
    int tb = (int)td[base + t];
    tb = min(max(tb, 0), 999);
#pragma unroll
    for (int hh = 0; hh < 4; ++hh) bias_s[hh][t] = temb[tb * 8 + hg * 4 + hh];
  }
  {
    const unsigned short* vp = qkv + (base + lane) * 1536 + 1024 + h * 64;
#pragma unroll
    for (int f8 = 0; f8 < 8; ++f8) {
      bf16x8 v8 = *(const bf16x8*)(vp + f8 * 8);
#pragma unroll
      for (int j = 0; j < 8; ++j) Vt_s[hl][f8 * 8 + j][lane] = (unsigned short)v8[j];
    }
  }
  __syncthreads();
  bf16x8 qa[2][4], kb[2][4];
#pragma unroll
  for (int ks = 0; ks < 2; ++ks)
#pragma unroll
    for (int i = 0; i < 4; ++i) {
      int row = i * 16 + (lane & 15);
      int kk = ks * 32 + (lane >> 4) * 8;
      qa[ks][i] = *(const bf16x8*)&qkv[(base + row) * 1536 + h * 64 + kk];
      kb[ks][i] = *(const bf16x8*)&qkv[(base + row) * 1536 + 512 + h * 64 + kk];
    }
  f32x4 acc[4][4] = {};
#pragma unroll
  for (int ks = 0; ks < 2; ++ks)
#pragma unroll
    for (int i = 0; i < 4; ++i)
#pragma unroll
      for (int j = 0; j < 4; ++j)
        acc[i][j] = __builtin_amdgcn_mfma_f32_16x16x32_bf16(qa[ks][i], kb[ks][j], acc[i][j], 0, 0, 0);
  float invs[4][4];
#pragma unroll
  for (int i = 0; i < 4; ++i) {
#pragma unroll
    for (int r = 0; r < 4; ++r) {
      float sv[4];
#pragma unroll
      for (int j = 0; j < 4; ++j) {
        int key = j * 16 + (lane & 15);
        float s = acc[i][j][r] * 0.125f;
        sv[j] = valid_s[key] ? (s + bias_s[hl][key]) : -1e9f;
      }
      float m = fmaxf(fmaxf(sv[0], sv[1]), fmaxf(sv[2], sv[3]));
#pragma unroll
      for (int off = 1; off < 16; off <<= 1) m = fmaxf(m, __shfl_xor(m, off, 64));
      float p[4], sum = 0.f;
#pragma unroll
      for (int j = 0; j < 4; ++j) { p[j] = __expf(sv[j] - m); sum += p[j]; }
#pragma unroll
      for (int off = 1; off < 16; off <<= 1) sum += __shfl_xor(sum, off, 64);
      invs[i][r] = 1.f / sum;
      int row = i * 16 + ((lane >> 4) << 2) + r;
#pragma unroll
      for (int j = 0; j < 4; ++j) P_s[hl][row][j * 16 + (lane & 15)] = f2bf(p[j]);
    }
  }
  __syncthreads();
  f32x4 acc2[4][4] = {};
#pragma unroll
  for (int ks = 0; ks < 2; ++ks) {
    bf16x8 pa[4], vb[4];
    int kk = ks * 32 + (lane >> 4) * 8;
#pragma unroll
    for (int i = 0; i < 4; ++i) {
      pa[i] = *(const bf16x8*)&P_s[hl][i * 16 + (lane & 15)][kk];
      vb[i] = *(const bf16x8*)&Vt_s[hl][i * 16 + (lane & 15)][kk];
    }
#pragma unroll
    for (int i = 0; i < 4; ++i)
#pragma unroll
      for (int j = 0; j < 4; ++j)
        acc2[i][j] = __builtin_amdgcn_mfma_f32_16x16x32_bf16(pa[i], vb[j], acc2[i][j], 0, 0, 0);
  }
  // coalesced epilogue: reuse own Vt_s[hl] (in-wave LDS deps only)
  unsigned short* scr = &Vt_s[hl][0][0];
#pragma unroll
  for (int i = 0; i < 4; ++i)
#pragma unroll
    for (int j = 0; j < 4; ++j)
#pragma unroll
      for (int r = 0; r < 4; ++r)
        scr[(i * 16 + ((lane >> 4) << 2) + r) * 72 + j * 16 + (lane & 15)] =
            f2bf(acc2[i][j][r] * invs[i][r]);
#pragma unroll
  for (int p = 0; p < 8; ++p) {
    int rl = p * 8 + (lane >> 3);
    bf16x8 vv = *(const bf16x8*)&scr[rl * 72 + (lane & 7) * 8];
    *(bf16x8*)&ctx[(base + rl) * 512 + h * 64 + (lane & 7) * 8] = vv;
  }
}

// ---------------- final: select last row, LN(e_g,e_bt), MLP, sigmoid. grid 8.
__global__ __launch_bounds__(256) void k_final(const unsigned short* __restrict__ proj2,
    const int* __restrict__ last_idx, const float* __restrict__ g, const float* __restrict__ bt,
    const float* __restrict__ w1, const float* __restrict__ b1,
    const float* __restrict__ w2, const float* __restrict__ b2, float* __restrict__ outp) {
  __shared__ float row_s[512];
  __shared__ float red_s[4];
  __shared__ float red2_s[4];
  int b = blockIdx.x, t = threadIdx.x;
  const unsigned short* rp = proj2 + (size_t)(b * 64 + last_idx[b]) * 512;
  float v0 = bf2f(rp[t]), v1 = bf2f(rp[t + 256]);
  float s = v0 + v1;
#pragma unroll
  for (int off = 1; off < 64; off <<= 1) s += __shfl_xor(s, off, 64);
  if ((t & 63) == 0) red_s[t >> 6] = s;
  __syncthreads();
  float mean = (red_s[0] + red_s[1] + red_s[2] + red_s[3]) * (1.f / 512.f);
  float d0 = v0 - mean, d1 = v1 - mean;
  float vs = d0 * d0 + d1 * d1;
#pragma unroll
  for (int off = 1; off < 64; off <<= 1) vs += __shfl_xor(vs, off, 64);
  if ((t & 63) == 0) red2_s[t >> 6] = vs;
  __syncthreads();
  float rstd = rsqrtf((red2_s[0] + red2_s[1] + red2_s[2] + red2_s[3]) * (1.f / 512.f) + 1e-5f);
  row_s[t]       = d0 * rstd * g[t]       + bt[t];
  row_s[t + 256] = d1 * rstd * g[t + 256] + bt[t + 256];
  __syncthreads();
  float acc = b1[t];
  for (int k = 0; k < 512; ++k) acc += row_s[k] * w1[(size_t)k * 256 + t];
  float hv = fmaxf(acc, 0.f) * w2[t];
#pragma unroll
  for (int off = 1; off < 64; off <<= 1) hv += __shfl_xor(hv, off, 64);
  if ((t & 63) == 0) red_s[t >> 6] = hv;
  __syncthreads();
  if (t == 0) {
    float o = red_s[0] + red_s[1] + red_s[2] + red_s[3] + b2[0];
    outp[b] = 1.f / (1.f + __expf(-o));
  }
}

extern "C" void kernel_launch(void* const* d_in, const int* in_sizes, int n_in,
                              void* d_out, int out_size, void* d_ws, size_t ws_size,
                              hipStream_t stream) {
  const int*   x    = (const int*)d_in[0];
  const float* td   = (const float*)d_in[1];
  const float* ee   = (const float*)d_in[2];
  const float* er   = (const float*)d_in[3];
  const float* ea   = (const float*)d_in[4];
  const float* iq_w = (const float*)d_in[5];  const float* iq_b = (const float*)d_in[6];
  const float* ik_w = (const float*)d_in[7];  const float* ik_b = (const float*)d_in[8];
  const float* iv_w = (const float*)d_in[9];  const float* iv_b = (const float*)d_in[10];
  const float* io_w = (const float*)d_in[11]; const float* io_b = (const float*)d_in[12];
  const float* eq_w = (const float*)d_in[13]; const float* eq_b = (const float*)d_in[14];
  const float* ek_w = (const float*)d_in[15]; const float* ek_b = (const float*)d_in[16];
  const float* ev_w = (const float*)d_in[17]; const float* ev_b = (const float*)d_in[18];
  const float* eo_w = (const float*)d_in[19]; const float* eo_b = (const float*)d_in[20];
  const float* i_temb = (const float*)d_in[21];
  const float* e_temb = (const float*)d_in[22];
  const float* i_g  = (const float*)d_in[23]; const float* i_bt = (const float*)d_in[24];
  const float* e_g  = (const float*)d_in[25]; const float* e_bt = (const float*)d_in[26];
  const float* w1   = (const float*)d_in[27]; const float* b1   = (const float*)d_in[28];
  const float* w2   = (const float*)d_in[29]; const float* b2   = (const float*)d_in[30];

  char* ws = (char*)d_ws;
  size_t off = 0;
  auto alloc = [&](size_t nb) { size_t r = off; off += (nb + 255) & ~(size_t)255; return r; };
  float* abs_t    = (float*)(ws + alloc((size_t)32768 * 4));
  float* bin_rel  = (float*)(ws + alloc(512 * 4));
  int*   bin_mask = (int*)(ws + alloc(512 * 4));
  int*   last_idx = (int*)(ws + alloc(64));
  unsigned short* wqkv_i = (unsigned short*)(ws + alloc((size_t)1536 * 512 * 2));
  unsigned short* wo_i   = (unsigned short*)(ws + alloc((size_t)512 * 512 * 2));
  unsigned short* wqkv_e = (unsigned short*)(ws + alloc((size_t)1536 * 512 * 2));
  unsigned short* wo_e   = (unsigned short*)(ws + alloc((size_t)512 * 512 * 2));
  float* bqkv_i = (float*)(ws + alloc(1536 * 4));
  float* bqkv_e = (float*)(ws + alloc(1536 * 4));
  unsigned short* hbuf = (unsigned short*)(ws + alloc((size_t)32768 * 512 * 2));   // h, then ctx
  unsigned short* qkvbuf = (unsigned short*)(ws + alloc((size_t)32768 * 1536 * 2));
  unsigned short* bin_repr = (unsigned short*)(ws + alloc((size_t)512 * 512 * 2));
  char* small = ws + alloc((size_t)512 * 1536 * 2);                                // qkv2, then proj2
  unsigned short* qkv2 = (unsigned short*)small;
  unsigned short* proj2 = (unsigned short*)small;
  unsigned short* ctx2 = (unsigned short*)(ws + alloc((size_t)512 * 512 * 2));

  // 1. pack weights + bias concats
  TPackArgs tp;
  tp.s[0] = iq_w; tp.d[0] = wqkv_i;
  tp.s[1] = ik_w; tp.d[1] = wqkv_i + (size_t)512 * 512;
  tp.s[2] = iv_w; tp.d[2] = wqkv_i + (size_t)1024 * 512;
  tp.s[3] = io_w; tp.d[3] = wo_i;
  tp.s[4] = eq_w; tp.d[4] = wqkv_e;
  tp.s[5] = ek_w; tp.d[5] = wqkv_e + (size_t)512 * 512;
  tp.s[6] = ev_w; tp.d[6] = wqkv_e + (size_t)1024 * 512;
  tp.s[7] = eo_w; tp.d[7] = wo_e;
  tp.bs[0] = iq_b; tp.bs[1] = ik_b; tp.bs[2] = iv_b;
  tp.bs[3] = eq_b; tp.bs[4] = ek_b; tp.bs[5] = ev_b;
  tp.bd[0] = bqkv_i; tp.bd[1] = bqkv_e;
  k_tpack8<<<513, 256, 0, stream>>>(tp);

  // 2. time features
  k_time<<<8, 64, 0, stream>>>(td, x, abs_t, bin_rel, bin_mask, last_idx);

  // 3. embeddings -> h
  k_embed<<<2048, 256, 0, stream>>>(x, td, abs_t, ee, er, ea, hbuf);

  // 4. intra path (256^2 BK=32 2-buf GEMM @ 2 blocks/CU; grid 768 %8==0)
  k_gemm256<<<128 * 6, 512, 0, stream>>>(hbuf, wqkv_i, bqkv_i, qkvbuf, 1536, 6);
  k_attn<<<1024, 256, 0, stream>>>(qkvbuf, td, x, i_temb, hbuf);                   // ctx -> hbuf
  k_oproj<<<256, 512, 0, stream>>>(hbuf, wo_i, io_b, x, i_g, i_bt, bin_repr);      // proj+LN+pool

  // 5. inter path
  k_gemm<<<4 * 12, 256, 0, stream>>>(bin_repr, wqkv_e, bqkv_e, qkv2, 1536, 12);
  k_attn<<<16, 256, 0, stream>>>(qkv2, bin_rel, bin_mask, e_temb, ctx2);
  k_gemm<<<4 * 4, 256, 0, stream>>>(ctx2, wo_e, eo_b, proj2, 512, 4);

  // 6. head
  k_final<<<8, 256, 0, stream>>>(proj2, last_idx, e_g, e_bt, w1, b1, w2, b2, (float*)d_out);
}

// Round 11
// 215.478 us; speedup vs baseline: 1.1104x; 1.0609x over previous
//
#include <hip/hip_runtime.h>

// HierarchicalChronoFormer forward, MI355X (gfx950).
// B=8, S=4096, D=512, H=8, dk=64, BIN=64, NB=64, T_BINS=1000.

typedef __attribute__((ext_vector_type(8))) short bf16x8;
typedef __attribute__((ext_vector_type(4))) float f32x4;
typedef __attribute__((ext_vector_type(4))) int i32x4;

#define DEVI __device__ __forceinline__

DEVI unsigned short f2bf(float f) {
  union { float f; unsigned u; } v; v.f = f;
  unsigned r = v.u + 0x7FFFu + ((v.u >> 16) & 1u);
  return (unsigned short)(r >> 16);
}
DEVI float bf2f(unsigned short u) {
  union { unsigned u; float f; } v; v.u = ((unsigned)u) << 16; return v.f;
}

#define GLOAD_LDS16(gp, lp) \
  __builtin_amdgcn_global_load_lds((const __attribute__((address_space(1))) void*)(gp), \
                                   (__attribute__((address_space(3))) void*)(lp), 16, 0, 0)

// ---------------- weight transpose-pack + bias concat + time features (one launch).
// blocks 0..511: Wt[n][k]=bf16(W[k][n]); block 512: bias concats; blocks 513..520: k_time.
struct TPackArgs { const float* s[8]; unsigned short* d[8];
                   const float* bs[6]; float* bd[2];
                   const float* td; const int* x;
                   float* abs_t; float* bin_rel; int* bin_mask; int* last_idx; };

__global__ __launch_bounds__(256) void k_tpack8(TPackArgs args) {
  __shared__ float shf[8192];                       // 32 KB, aliased per role
  int t = threadIdx.x;
  if (blockIdx.x == 512) {
    for (int i = t; i < 1536; i += 256) {
      int sel = i >> 9, r = i & 511;
      args.bd[0][i] = args.bs[sel][r];
      args.bd[1][i] = args.bs[3 + sel][r];
    }
    return;
  }
  if (blockIdx.x >= 513) {                          // time features for batch b
    int b = blockIdx.x - 513;
    float* tds = shf;
    int* xs = (int*)(shf + 4096);
    const f32x4* tp = (const f32x4*)(args.td + (size_t)b * 4096);
    const i32x4* xp = (const i32x4*)(args.x + (size_t)b * 4096);
    for (int j = t; j < 1024; j += 256) {
      f32x4 v = tp[j];
#pragma unroll
      for (int c = 0; c < 4; ++c) v[c] = fmaxf(v[c], 0.f);
      *(f32x4*)&tds[j * 4] = v;
      *(i32x4*)&xs[j * 4] = xp[j];
    }
    __syncthreads();
    if (t < 64) {
      int lane = t;
      float s = 0.f;
      for (int i = 0; i < 64; ++i) s += tds[lane * 64 + i];
      float pre = s;
#pragma unroll
      for (int off = 1; off < 64; off <<= 1) {
        float n = __shfl_up(pre, off, 64);
        if (lane >= off) pre += n;
      }
      float a = pre - s;                            // exclusive prefix
      float am = 0.f; int anyv = 0;
      for (int i = 0; i < 64; ++i) {
        a += tds[lane * 64 + i];
        tds[lane * 64 + i] = a;                     // overwrite with cumsum
        if (xs[lane * 64 + i] != 0) { am = fmaxf(am, a); anyv = 1; }
      }
      float prev = __shfl_up(am, 1, 64);
      args.bin_rel[b * 64 + lane] = (lane == 0) ? 0.f : fmaxf(am - prev, 0.f);
      args.bin_mask[b * 64 + lane] = anyv;
      unsigned long long bal = __ballot(anyv != 0);
      if (lane == 0) args.last_idx[b] = max(__popcll(bal) - 1, 0);
    }
    __syncthreads();
    float* out = args.abs_t + (size_t)b * 4096;
    for (int j = t; j < 1024; j += 256)
      *(f32x4*)&out[j * 4] = *(const f32x4*)&tds[j * 4];
    return;
  }
  // weight transpose-pack
  float (*tile)[65] = (float(*)[65])shf;
  int mat = blockIdx.x >> 6;
  int tl = blockIdx.x & 63;
  const float* W = args.s[mat];
  unsigned short* Wt = args.d[mat];
  int n0 = (tl & 7) << 6, k0 = (tl >> 3) << 6;
  int j = t & 63, i0 = t >> 6;
#pragma unroll
  for (int rr = 0; rr < 16; ++rr) {
    int i = rr * 4 + i0;
    tile[i][j] = W[(size_t)(k0 + i) * 512 + n0 + j];
  }
  __syncthreads();
#pragma unroll
  for (int rr = 0; rr < 16; ++rr) {
    int i = rr * 4 + i0;
    Wt[(size_t)(n0 + i) * 512 + k0 + j] = f2bf(tile[j][i]);
  }
}

// ---------------- h = ee[x] (0 if x==0) + emb_rel[rb] + emb_abs[ab], bf16 out. 16 tok/block.
__global__ __launch_bounds__(256) void k_embed(const int* __restrict__ x, const float* __restrict__ td,
    const float* __restrict__ abs_t, const float* __restrict__ ee, const float* __restrict__ er,
    const float* __restrict__ ea, unsigned short* __restrict__ h) {
  int t = threadIdx.x;
  int lane = t & 63;
  int c0 = lane * 8;
#pragma unroll
  for (int it = 0; it < 4; ++it) {
    int tok = blockIdx.x * 16 + it * 4 + (t >> 6);
    int xi = x[tok];
    int rb = (int)td[tok]; rb = min(max(rb, 0), 999);
    int ab = (int)abs_t[tok]; ab = min(max(ab, 0), 999);
    const f32x4* pr = (const f32x4*)(er + (size_t)rb * 512 + c0);
    const f32x4* pa = (const f32x4*)(ea + (size_t)ab * 512 + c0);
    f32x4 s0 = pr[0] + pa[0];
    f32x4 s1 = pr[1] + pa[1];
    if (xi != 0) {
      const f32x4* pe = (const f32x4*)(ee + (size_t)xi * 512 + c0);
      s0 += pe[0]; s1 += pe[1];
    }
    bf16x8 o;
#pragma unroll
    for (int i = 0; i < 4; ++i) { o[i] = (short)f2bf(s0[i]); o[4 + i] = (short)f2bf(s1[i]); }
    *(bf16x8*)(h + (size_t)tok * 512 + c0) = o;
  }
}

// ---------------- swizzle helpers
DEVI bf16x8 lds_frag32(const unsigned short* buf, int r, int g) {
  int sr = r >> 1;
  int slot = (((r & 1) << 2) | g) ^ (sr & 7);
  return *(const bf16x8*)&buf[sr * 64 + slot * 8];
}
DEVI bf16x8 lds_frag64(const unsigned short* buf, int row, int c) {
  return *(const bf16x8*)&buf[row * 64 + ((c ^ (row & 7)) << 3)];
}

// ---------------- big GEMM (QKV): 128x256 tile, 8 waves of 64x64 (acc=64 f32/lane),
// launch_bounds(512,4) -> <=128 regs/wave -> 16 waves/CU = 2 co-resident blocks.
// BK=64 single-buffered m97-style 2-barrier loop; row-XOR-64 both-sides swizzle.
__global__ __launch_bounds__(512, 4) void k_gemm256(const unsigned short* __restrict__ A,
    const unsigned short* __restrict__ Wt, const float* __restrict__ bias,
    unsigned short* __restrict__ Cout, int N, int tiles_n) {
  __shared__ unsigned short As[128 * 64];   // 16 KB
  __shared__ unsigned short Bs[256 * 64];   // 32 KB
  int bid = blockIdx.x;
  { int q = (int)gridDim.x >> 3; bid = (bid & 7) * q + (bid >> 3); }  // grid %8==0
  int by = bid / tiles_n, bx = bid % tiles_n;
  int m0 = by << 7, n0 = bx << 8;
  int t = threadIdx.x;
  int lane = t & 63, w = t >> 6;
  int wm = w >> 2, wn = w & 3;              // wave tile: rows wm*64..+63, cols wn*64..+63
  int l15 = lane & 15, l4 = lane >> 4;

  f32x4 acc[4][4] = {};
  for (int k0 = 0; k0 < 512; k0 += 64) {
    __syncthreads();                         // prev tile's reads done before overwrite
#pragma unroll
    for (int l = 0; l < 2; ++l) {            // A: 1024 granules
      int pos = l * 512 + t;
      int row = pos >> 3, g = (pos & 7) ^ (row & 7);
      GLOAD_LDS16(&A[(size_t)(m0 + row) * 512 + k0 + g * 8], &As[pos * 8]);
    }
#pragma unroll
    for (int l = 0; l < 4; ++l) {            // B: 2048 granules
      int pos = l * 512 + t;
      int row = pos >> 3, g = (pos & 7) ^ (row & 7);
      GLOAD_LDS16(&Wt[(size_t)(n0 + row) * 512 + k0 + g * 8], &Bs[pos * 8]);
    }
    __syncthreads();                         // compiler drains vmcnt before barrier
#pragma unroll
    for (int ks = 0; ks < 2; ++ks) {
      bf16x8 af[4], bb[4];
#pragma unroll
      for (int i = 0; i < 4; ++i) {
        af[i] = lds_frag64(As, wm * 64 + i * 16 + l15, ks * 4 + l4);
        bb[i] = lds_frag64(Bs, wn * 64 + i * 16 + l15, ks * 4 + l4);
      }
      __builtin_amdgcn_s_setprio(1);
#pragma unroll
      for (int i = 0; i < 4; ++i)
#pragma unroll
        for (int j = 0; j < 4; ++j)
          acc[i][j] = __builtin_amdgcn_mfma_f32_16x16x32_bf16(af[i], bb[j], acc[i][j], 0, 0, 0);
      __builtin_amdgcn_s_setprio(0);
    }
  }
#pragma unroll
  for (int i = 0; i < 4; ++i) {
    int rowb = m0 + wm * 64 + i * 16 + (l4 << 2);
#pragma unroll
    for (int j = 0; j < 4; ++j) {
      int col = n0 + wn * 64 + j * 16 + l15;
      float bv = bias[col];
#pragma unroll
      for (int r = 0; r < 4; ++r)
        Cout[(size_t)(rowb + r) * N + col] = f2bf(acc[i][j][r] + bv);
    }
  }
}

// ---------------- fused out-proj + LN + masked pool: BM=128, BN=512 (all Wo), BK=32.
// A 4-buf (32KB) + B 2-buf (64KB). 8 waves (1Mx8N). Counted-vmcnt pipeline (r6/r10 best).
__global__ __launch_bounds__(512, 2) void k_oproj(const unsigned short* __restrict__ ctx,
    const unsigned short* __restrict__ WoT, const float* __restrict__ bo,
    const int* __restrict__ x, const float* __restrict__ g, const float* __restrict__ bt,
    unsigned short* __restrict__ bin_repr) {
  __shared__ unsigned short ldsA[4][128 * 32];
  __shared__ unsigned short ldsB[2][512 * 32];
  int bid = blockIdx.x;
  { int q = (int)gridDim.x >> 3; bid = (bid & 7) * q + (bid >> 3); }  // grid 256 %8==0
  int m0 = bid << 7;
  int t = threadIdx.x;
  int lane = t & 63, w = t >> 6;          // w = wn (cols w*64..+63), rows 0..127 all waves
  int l15 = lane & 15, l4 = lane >> 4;

  auto stageA = [&](int kt) {
    int k0 = kt << 5;
    unsigned short* dst = &ldsA[kt & 3][0];
    int pos = t;
    int sr = pos >> 3, slot = pos & 7;
    int gp = slot ^ (sr & 7);
    int row = sr * 2 + (gp >> 2);
    GLOAD_LDS16(&ctx[(size_t)(m0 + row) * 512 + k0 + (gp & 3) * 8], dst + pos * 8);
  };
  auto stageB = [&](int kt) {
    int k0 = kt << 5;
    unsigned short* dst = &ldsB[kt & 1][0];
#pragma unroll
    for (int l = 0; l < 4; ++l) {
      int pos = l * 512 + t;
      int sr = pos >> 3, slot = pos & 7;
      int gp = slot ^ (sr & 7);
      int row = sr * 2 + (gp >> 2);
      GLOAD_LDS16(&WoT[(size_t)row * 512 + k0 + (gp & 3) * 8], dst + pos * 8);
    }
  };

  f32x4 acc[8][4] = {};
  stageB(0); stageA(0); stageA(1); stageA(2); stageB(1);

  for (int kt = 0; kt < 16; ++kt) {
    if (kt == 0)      asm volatile("s_waitcnt vmcnt(6)" ::: "memory");
    else if (kt < 14) asm volatile("s_waitcnt vmcnt(1)" ::: "memory");
    else              asm volatile("s_waitcnt vmcnt(0)" ::: "memory");
    __builtin_amdgcn_s_barrier();
    const unsigned short* As = &ldsA[kt & 3][0];
    const unsigned short* Bs = &ldsB[kt & 1][0];

    bf16x8 af[4], bb[4];
#pragma unroll
    for (int i = 0; i < 4; ++i) af[i] = lds_frag32(As, i * 16 + l15, l4);
#pragma unroll
    for (int j = 0; j < 4; ++j) bb[j] = lds_frag32(Bs, w * 64 + j * 16 + l15, l4);
    if (kt >= 1 && kt <= 14) stageB(kt + 1);
    __builtin_amdgcn_s_barrier();
    asm volatile("s_waitcnt lgkmcnt(0)" ::: "memory");
    __builtin_amdgcn_sched_barrier(0);
    __builtin_amdgcn_s_setprio(1);
#pragma unroll
    for (int i = 0; i < 4; ++i)
#pragma unroll
      for (int j = 0; j < 4; ++j)
        acc[i][j] = __builtin_amdgcn_mfma_f32_16x16x32_bf16(af[i], bb[j], acc[i][j], 0, 0, 0);
    __builtin_amdgcn_s_setprio(0);

    bf16x8 ah[4];
#pragma unroll
    for (int i = 0; i < 4; ++i) ah[i] = lds_frag32(As, 64 + i * 16 + l15, l4);
    if (kt <= 12) stageA(kt + 3);
    __builtin_amdgcn_s_barrier();
    asm volatile("s_waitcnt lgkmcnt(0)" ::: "memory");
    __builtin_amdgcn_sched_barrier(0);
    __builtin_amdgcn_s_setprio(1);
#pragma unroll
    for (int i = 0; i < 4; ++i)
#pragma unroll
      for (int j = 0; j < 4; ++j)
        acc[4 + i][j] = __builtin_amdgcn_mfma_f32_16x16x32_bf16(ah[i], bb[j], acc[4 + i][j], 0, 0, 0);
    __builtin_amdgcn_s_setprio(0);
  }

  // -------- epilogue: bias + LN (f32) + masked mean-pool of 2 bins -> bin_repr
  __syncthreads();
  float* red   = (float*)&ldsA[0][0];    // [128][9]
  float* meanL = red + 128 * 9;
  float* rstdL = meanL + 128;
  int*   valL  = (int*)(rstdL + 128);
  int*   cntL  = valL + 128;

  int cols[4]; float bov[4], gv[4], bv[4];
#pragma unroll
  for (int j = 0; j < 4; ++j) {
    cols[j] = w * 64 + j * 16 + l15;
    bov[j] = bo[cols[j]]; gv[j] = g[cols[j]]; bv[j] = bt[cols[j]];
  }
  if (t < 128) {
    int v = (x[m0 + t] != 0) ? 1 : 0;
    valL[t] = v;
    unsigned long long bal = __ballot(v != 0);
    if ((t & 63) == 0) cntL[t >> 6] = __popcll(bal);
  }
#pragma unroll
  for (int i = 0; i < 8; ++i)
#pragma unroll
    for (int r = 0; r < 4; ++r) {
      float s = (acc[i][0][r] + bov[0]) + (acc[i][1][r] + bov[1]) +
                (acc[i][2][r] + bov[2]) + (acc[i][3][r] + bov[3]);
#pragma unroll
      for (int off = 1; off < 16; off <<= 1) s += __shfl_xor(s, off, 64);
      if (l15 == 0) red[(i * 16 + l4 * 4 + r) * 9 + w] = s;
    }
  __syncthreads();
  if (t < 128) {
    float m = 0.f;
#pragma unroll
    for (int ww = 0; ww < 8; ++ww) m += red[t * 9 + ww];
    meanL[t] = m * (1.f / 512.f);
  }
  __syncthreads();
#pragma unroll
  for (int i = 0; i < 8; ++i)
#pragma unroll
    for (int r = 0; r < 4; ++r) {
      float m = meanL[i * 16 + l4 * 4 + r];
      float s = 0.f;
#pragma unroll
      for (int j = 0; j < 4; ++j) { float d = acc[i][j][r] + bov[j] - m; s += d * d; }
#pragma unroll
      for (int off = 1; off < 16; off <<= 1) s += __shfl_xor(s, off, 64);
      if (l15 == 0) red[(i * 16 + l4 * 4 + r) * 9 + w] = s;
    }
  __syncthreads();
  if (t < 128) {
    float vsum = 0.f;
#pragma unroll
    for (int ww = 0; ww < 8; ++ww) vsum += red[t * 9 + ww];
    rstdL[t] = rsqrtf(vsum * (1.f / 512.f) + 1e-5f);
  }
  __syncthreads();
  float p0[4] = {0.f, 0.f, 0.f, 0.f}, p1[4] = {0.f, 0.f, 0.f, 0.f};
#pragma unroll
  for (int i = 0; i < 8; ++i)
#pragma unroll
    for (int r = 0; r < 4; ++r) {
      int row = i * 16 + l4 * 4 + r;
      if (valL[row]) {
        float m = meanL[row], rs = rstdL[row];
#pragma unroll
        for (int j = 0; j < 4; ++j) {
          float y = (acc[i][j][r] + bov[j] - m) * rs * gv[j] + bv[j];
          if (i < 4) p0[j] += y; else p1[j] += y;
        }
      }
    }
#pragma unroll
  for (int j = 0; j < 4; ++j) {
    p0[j] += __shfl_xor(p0[j], 16, 64); p0[j] += __shfl_xor(p0[j], 32, 64);
    p1[j] += __shfl_xor(p1[j], 16, 64); p1[j] += __shfl_xor(p1[j], 32, 64);
  }
  float d0 = 1.f / fmaxf((float)cntL[0], 1.f);
  float d1 = 1.f / fmaxf((float)cntL[1], 1.f);
  if (l4 == 0) {
    int binr = (m0 >> 6);
#pragma unroll
    for (int j = 0; j < 4; ++j) {
      bin_repr[(size_t)binr * 512 + cols[j]]       = f2bf(p0[j] * d0);
      bin_repr[(size_t)(binr + 1) * 512 + cols[j]] = f2bf(p1[j] * d1);
    }
  }
}

// ---------------- small GEMM (inter path): 128x128 tile, reg-staged padded LDS.
__global__ __launch_bounds__(256) void k_gemm(const unsigned short* __restrict__ A,
    const unsigned short* __restrict__ Wt, const float* __restrict__ bias,
    unsigned short* __restrict__ Cout, int N, int tiles_n) {
  __shared__ unsigned short As[128 * 72];
  __shared__ unsigned short Bs[128 * 72];
  int bx = blockIdx.x % tiles_n;
  int by = blockIdx.x / tiles_n;
  int m0 = by << 7, n0 = bx << 7;
  int t = threadIdx.x;
  int lane = t & 63, w = t >> 6;
  int wm = w >> 1, wn = w & 1;
  f32x4 acc[4][4] = {};
  for (int k0 = 0; k0 < 512; k0 += 64) {
    __syncthreads();
#pragma unroll
    for (int i = 0; i < 4; ++i) {
      int idx = t + i * 256;
      int row = idx >> 3, seg = idx & 7;
      *(bf16x8*)&As[row * 72 + seg * 8] = *(const bf16x8*)&A[(size_t)(m0 + row) * 512 + k0 + seg * 8];
      *(bf16x8*)&Bs[row * 72 + seg * 8] = *(const bf16x8*)&Wt[(size_t)(n0 + row) * 512 + k0 + seg * 8];
    }
    __syncthreads();
#pragma unroll
    for (int ks = 0; ks < 2; ++ks) {
      bf16x8 af[4], bb[4];
#pragma unroll
      for (int i = 0; i < 4; ++i) {
        af[i] = *(const bf16x8*)&As[(wm * 64 + i * 16 + (lane & 15)) * 72 + ks * 32 + (lane >> 4) * 8];
        bb[i] = *(const bf16x8*)&Bs[(wn * 64 + i * 16 + (lane & 15)) * 72 + ks * 32 + (lane >> 4) * 8];
      }
#pragma unroll
      for (int i = 0; i < 4; ++i)
#pragma unroll
        for (int j = 0; j < 4; ++j)
          acc[i][j] = __builtin_amdgcn_mfma_f32_16x16x32_bf16(af[i], bb[j], acc[i][j], 0, 0, 0);
    }
  }
#pragma unroll
  for (int i = 0; i < 4; ++i) {
    int rowb = m0 + wm * 64 + i * 16 + ((lane >> 4) << 2);
#pragma unroll
    for (int j = 0; j < 4; ++j) {
      int col = n0 + wn * 64 + j * 16 + (lane & 15);
      float bv = bias[col];
#pragma unroll
      for (int r = 0; r < 4; ++r)
        Cout[(size_t)(rowb + r) * N + col] = f2bf(acc[i][j][r] + bv);
    }
  }
}

// ---------------- fused attention; block = 4 heads of one 64-token bin (2 blocks/bin).
// Deferred softmax normalization; coalesced LDS-transpose epilogue.
__global__ __launch_bounds__(256) void k_attn(const unsigned short* __restrict__ qkv,
    const float* __restrict__ td, const int* __restrict__ validv,
    const float* __restrict__ temb, unsigned short* __restrict__ ctx) {
  __shared__ float bias_s[4][64];
  __shared__ int valid_s[64];
  __shared__ unsigned short P_s[4][64][72];
  __shared__ unsigned short Vt_s[4][64][72];
  int blk = blockIdx.x >> 1, hg = blockIdx.x & 1;
  int t = threadIdx.x, hl = t >> 6, lane = t & 63;
  int h = hg * 4 + hl;
  size_t base = (size_t)blk * 64;
  if (t < 64) {
    valid_s[t] = (validv[base + t] != 0) ? 1 : 0;
    int tb = (int)td[base + t];
    tb = min(max(tb, 0), 999);
#pragma unroll
    for (int hh = 0; hh < 4; ++hh) bias_s[hh][t] = temb[tb * 8 + hg * 4 + hh];
  }
  {
    const unsigned short* vp = qkv + (base + lane) * 1536 + 1024 + h * 64;
#pragma unroll
    for (int f8 = 0; f8 < 8; ++f8) {
      bf16x8 v8 = *(const bf16x8*)(vp + f8 * 8);
#pragma unroll
      for (int j = 0; j < 8; ++j) Vt_s[hl][f8 * 8 + j][lane] = (unsigned short)v8[j];
    }
  }
  __syncthreads();
  bf16x8 qa[2][4], kb[2][4];
#pragma unroll
  for (int ks = 0; ks < 2; ++ks)
#pragma unroll
    for (int i = 0; i < 4; ++i) {
      int row = i * 16 + (lane & 15);
      int kk = ks * 32 + (lane >> 4) * 8;
      qa[ks][i] = *(const bf16x8*)&qkv[(base + row) * 1536 + h * 64 + kk];
      kb[ks][i] = *(const bf16x8*)&qkv[(base + row) * 1536 + 512 + h * 64 + kk];
    }
  f32x4 acc[4][4] = {};
#pragma unroll
  for (int ks = 0; ks < 2; ++ks)
#pragma unroll
    for (int i = 0; i < 4; ++i)
#pragma unroll
      for (int j = 0; j < 4; ++j)
        acc[i][j] = __builtin_amdgcn_mfma_f32_16x16x32_bf16(qa[ks][i], kb[ks][j], acc[i][j], 0, 0, 0);
  float invs[4][4];
#pragma unroll
  for (int i = 0; i < 4; ++i) {
#pragma unroll
    for (int r = 0; r < 4; ++r) {
      float sv[4];
#pragma unroll
      for (int j = 0; j < 4; ++j) {
        int key = j * 16 + (lane & 15);
        float s = acc[i][j][r] * 0.125f;
        sv[j] = valid_s[key] ? (s + bias_s[hl][key]) : -1e9f;
      }
      float m = fmaxf(fmaxf(sv[0], sv[1]), fmaxf(sv[2], sv[3]));
#pragma unroll
      for (int off = 1; off < 16; off <<= 1) m = fmaxf(m, __shfl_xor(m, off, 64));
      float p[4], sum = 0.f;
#pragma unroll
      for (int j = 0; j < 4; ++j) { p[j] = __expf(sv[j] - m); sum += p[j]; }
#pragma unroll
      for (int off = 1; off < 16; off <<= 1) sum += __shfl_xor(sum, off, 64);
      invs[i][r] = 1.f / sum;
      int row = i * 16 + ((lane >> 4) << 2) + r;
#pragma unroll
      for (int j = 0; j < 4; ++j) P_s[hl][row][j * 16 + (lane & 15)] = f2bf(p[j]);
    }
  }
  __syncthreads();
  f32x4 acc2[4][4] = {};
#pragma unroll
  for (int ks = 0; ks < 2; ++ks) {
    bf16x8 pa[4], vb[4];
    int kk = ks * 32 + (lane >> 4) * 8;
#pragma unroll
    for (int i = 0; i < 4; ++i) {
      pa[i] = *(const bf16x8*)&P_s[hl][i * 16 + (lane & 15)][kk];
      vb[i] = *(const bf16x8*)&Vt_s[hl][i * 16 + (lane & 15)][kk];
    }
#pragma unroll
    for (int i = 0; i < 4; ++i)
#pragma unroll
      for (int j = 0; j < 4; ++j)
        acc2[i][j] = __builtin_amdgcn_mfma_f32_16x16x32_bf16(pa[i], vb[j], acc2[i][j], 0, 0, 0);
  }
  unsigned short* scr = &Vt_s[hl][0][0];
#pragma unroll
  for (int i = 0; i < 4; ++i)
#pragma unroll
    for (int j = 0; j < 4; ++j)
#pragma unroll
      for (int r = 0; r < 4; ++r)
        scr[(i * 16 + ((lane >> 4) << 2) + r) * 72 + j * 16 + (lane & 15)] =
            f2bf(acc2[i][j][r] * invs[i][r]);
#pragma unroll
  for (int p = 0; p < 8; ++p) {
    int rl = p * 8 + (lane >> 3);
    bf16x8 vv = *(const bf16x8*)&scr[rl * 72 + (lane & 7) * 8];
    *(bf16x8*)&ctx[(base + rl) * 512 + h * 64 + (lane & 7) * 8] = vv;
  }
}

// ---------------- final: select last row, LN(e_g,e_bt), MLP, sigmoid. grid 8.
__global__ __launch_bounds__(256) void k_final(const unsigned short* __restrict__ proj2,
    const int* __restrict__ last_idx, const float* __restrict__ g, const float* __restrict__ bt,
    const float* __restrict__ w1, const float* __restrict__ b1,
    const float* __restrict__ w2, const float* __restrict__ b2, float* __restrict__ outp) {
  __shared__ float row_s[512];
  __shared__ float red_s[4];
  __shared__ float red2_s[4];
  int b = blockIdx.x, t = threadIdx.x;
  const unsigned short* rp = proj2 + (size_t)(b * 64 + last_idx[b]) * 512;
  float v0 = bf2f(rp[t]), v1 = bf2f(rp[t + 256]);
  float s = v0 + v1;
#pragma unroll
  for (int off = 1; off < 64; off <<= 1) s += __shfl_xor(s, off, 64);
  if ((t & 63) == 0) red_s[t >> 6] = s;
  __syncthreads();
  float mean = (red_s[0] + red_s[1] + red_s[2] + red_s[3]) * (1.f / 512.f);
  float d0 = v0 - mean, d1 = v1 - mean;
  float vs = d0 * d0 + d1 * d1;
#pragma unroll
  for (int off = 1; off < 64; off <<= 1) vs += __shfl_xor(vs, off, 64);
  if ((t & 63) == 0) red2_s[t >> 6] = vs;
  __syncthreads();
  float rstd = rsqrtf((red2_s[0] + red2_s[1] + red2_s[2] + red2_s[3]) * (1.f / 512.f) + 1e-5f);
  row_s[t]       = d0 * rstd * g[t]       + bt[t];
  row_s[t + 256] = d1 * rstd * g[t + 256] + bt[t + 256];
  __syncthreads();
  float acc = b1[t];
  for (int k = 0; k < 512; ++k) acc += row_s[k] * w1[(size_t)k * 256 + t];
  float hv = fmaxf(acc, 0.f) * w2[t];
#pragma unroll
  for (int off = 1; off < 64; off <<= 1) hv += __shfl_xor(hv, off, 64);
  if ((t & 63) == 0) red_s[t >> 6] = hv;
  __syncthreads();
  if (t == 0) {
    float o = red_s[0] + red_s[1] + red_s[2] + red_s[3] + b2[0];
    outp[b] = 1.f / (1.f + __expf(-o));
  }
}

extern "C" void kernel_launch(void* const* d_in, const int* in_sizes, int n_in,
                              void* d_out, int out_size, void* d_ws, size_t ws_size,
                              hipStream_t stream) {
  const int*   x    = (const int*)d_in[0];
  const float* td   = (const float*)d_in[1];
  const float* ee   = (const float*)d_in[2];
  const float* er   = (const float*)d_in[3];
  const float* ea   = (const float*)d_in[4];
  const float* iq_w = (const float*)d_in[5];  const float* iq_b = (const float*)d_in[6];
  const float* ik_w = (const float*)d_in[7];  const float* ik_b = (const float*)d_in[8];
  const float* iv_w = (const float*)d_in[9];  const float* iv_b = (const float*)d_in[10];
  const float* io_w = (const float*)d_in[11]; const float* io_b = (const float*)d_in[12];
  const float* eq_w = (const float*)d_in[13]; const float* eq_b = (const float*)d_in[14];
  const float* ek_w = (const float*)d_in[15]; const float* ek_b = (const float*)d_in[16];
  const float* ev_w = (const float*)d_in[17]; const float* ev_b = (const float*)d_in[18];
  const float* eo_w = (const float*)d_in[19]; const float* eo_b = (const float*)d_in[20];
  const float* i_temb = (const float*)d_in[21];
  const float* e_temb = (const float*)d_in[22];
  const float* i_g  = (const float*)d_in[23]; const float* i_bt = (const float*)d_in[24];
  const float* e_g  = (const float*)d_in[25]; const float* e_bt = (const float*)d_in[26];
  const float* w1   = (const float*)d_in[27]; const float* b1   = (const float*)d_in[28];
  const float* w2   = (const float*)d_in[29]; const float* b2   = (const float*)d_in[30];

  char* ws = (char*)d_ws;
  size_t off = 0;
  auto alloc = [&](size_t nb) { size_t r = off; off += (nb + 255) & ~(size_t)255; return r; };
  float* abs_t    = (float*)(ws + alloc((size_t)32768 * 4));
  float* bin_rel  = (float*)(ws + alloc(512 * 4));
  int*   bin_mask = (int*)(ws + alloc(512 * 4));
  int*   last_idx = (int*)(ws + alloc(64));
  unsigned short* wqkv_i = (unsigned short*)(ws + alloc((size_t)1536 * 512 * 2));
  unsigned short* wo_i   = (unsigned short*)(ws + alloc((size_t)512 * 512 * 2));
  unsigned short* wqkv_e = (unsigned short*)(ws + alloc((size_t)1536 * 512 * 2));
  unsigned short* wo_e   = (unsigned short*)(ws + alloc((size_t)512 * 512 * 2));
  float* bqkv_i = (float*)(ws + alloc(1536 * 4));
  float* bqkv_e = (float*)(ws + alloc(1536 * 4));
  unsigned short* hbuf = (unsigned short*)(ws + alloc((size_t)32768 * 512 * 2));   // h, then ctx
  unsigned short* qkvbuf = (unsigned short*)(ws + alloc((size_t)32768 * 1536 * 2));
  unsigned short* bin_repr = (unsigned short*)(ws + alloc((size_t)512 * 512 * 2));
  char* small = ws + alloc((size_t)512 * 1536 * 2);                                // qkv2, then proj2
  unsigned short* qkv2 = (unsigned short*)small;
  unsigned short* proj2 = (unsigned short*)small;
  unsigned short* ctx2 = (unsigned short*)(ws + alloc((size_t)512 * 512 * 2));

  // 1. pack weights + bias concats + time features (one launch)
  TPackArgs tp;
  tp.s[0] = iq_w; tp.d[0] = wqkv_i;
  tp.s[1] = ik_w; tp.d[1] = wqkv_i + (size_t)512 * 512;
  tp.s[2] = iv_w; tp.d[2] = wqkv_i + (size_t)1024 * 512;
  tp.s[3] = io_w; tp.d[3] = wo_i;
  tp.s[4] = eq_w; tp.d[4] = wqkv_e;
  tp.s[5] = ek_w; tp.d[5] = wqkv_e + (size_t)512 * 512;
  tp.s[6] = ev_w; tp.d[6] = wqkv_e + (size_t)1024 * 512;
  tp.s[7] = eo_w; tp.d[7] = wo_e;
  tp.bs[0] = iq_b; tp.bs[1] = ik_b; tp.bs[2] = iv_b;
  tp.bs[3] = eq_b; tp.bs[4] = ek_b; tp.bs[5] = ev_b;
  tp.bd[0] = bqkv_i; tp.bd[1] = bqkv_e;
  tp.td = td; tp.x = x;
  tp.abs_t = abs_t; tp.bin_rel = bin_rel; tp.bin_mask = bin_mask; tp.last_idx = last_idx;
  k_tpack8<<<521, 256, 0, stream>>>(tp);

  // 2. embeddings -> h
  k_embed<<<2048, 256, 0, stream>>>(x, td, abs_t, ee, er, ea, hbuf);

  // 3. intra path (128x256-tile GEMM, 16 waves/CU target; grid 1536 %8==0)
  k_gemm256<<<256 * 6, 512, 0, stream>>>(hbuf, wqkv_i, bqkv_i, qkvbuf, 1536, 6);
  k_attn<<<1024, 256, 0, stream>>>(qkvbuf, td, x, i_temb, hbuf);                   // ctx -> hbuf
  k_oproj<<<256, 512, 0, stream>>>(hbuf, wo_i, io_b, x, i_g, i_bt, bin_repr);      // proj+LN+pool

  // 4. inter path
  k_gemm<<<4 * 12, 256, 0, stream>>>(bin_repr, wqkv_e, bqkv_e, qkv2, 1536, 12);
  k_attn<<<16, 256, 0, stream>>>(qkv2, bin_rel, bin_mask, e_temb, ctx2);
  k_gemm<<<4 * 4, 256, 0, stream>>>(ctx2, wo_e, eo_b, proj2, 512, 4);

  // 5. head
  k_final<<<8, 256, 0, stream>>>(proj2, last_idx, e_g, e_bt, w1, b1, w2, b2, (float*)d_out);
}